// Round 12
// baseline (842.780 us; speedup 1.0000x reference)
//
#include <hip/hip_runtime.h>
#include <math.h>

constexpr int Bc = 16;
constexpr int Nc = 8192;
constexpr int Sc = 512;
constexpr int Kc = 32;
constexpr int Pc = Bc * Sc * Kc; // 262144

constexpr int NBALL_BLK = 240;             // ball blocks (+16 FPS = 256 total)
constexpr int NBALL_WAVES = NBALL_BLK * 4; // 960 (60 waves per batch, stride 60)

typedef float v2f __attribute__((ext_vector_type(2)));

#if defined(__has_builtin)
#if __has_builtin(__builtin_elementwise_fma)
#define PKFMA(a, b, c) __builtin_elementwise_fma(a, b, c)
#endif
#endif
#ifndef PKFMA
__device__ __forceinline__ v2f pkfma_(v2f a, v2f b, v2f c) {
  v2f r; r.x = fmaf(a.x, b.x, c.x); r.y = fmaf(a.y, b.y, c.y); return r;
}
#define PKFMA(a, b, c) pkfma_(a, b, c)
#endif

// DPP-assisted wave64 max stage (ctrl is a compile-time constant)
template <int CTRL>
__device__ __forceinline__ float dpp_max_stage(float x) {
  int p = __builtin_amdgcn_update_dpp(0, __float_as_int(x), CTRL, 0xf, 0xf, true);
  return fmaxf(x, __int_as_float(p));
}

// ---------------------------------------------------------------------------
// Fused FPS + ball query producer/consumer kernel — EXACT round-0 config
// (measured 486-495us, stable across r1/r2/r5/r7-r11). Do not touch.
// ---------------------------------------------------------------------------
__global__ __launch_bounds__(256, 1)
void fps_ball_fused(const float* __restrict__ data,
                    const float* __restrict__ feat,
                    const float* __restrict__ w0,
                    const float* __restrict__ b0,
                    int* __restrict__ idx_pub,
                    float* __restrict__ cent_out,
                    float* __restrict__ x0,
                    float* __restrict__ part0) {
  __shared__ float lx[Nc], ly[Nc], lz[Nc];          // 96 KB point mirror (FPS)
  __shared__ unsigned long long red_k[2][4];
  __shared__ int idx_hist[Sc];
  __shared__ int nbr[4][Kc];                        // per-wave (ball)
  __shared__ float x0s[4][6][Kc];                   // per-wave (ball)

  const int t = threadIdx.x;
  const int lane = t & 63, w = t >> 6;

  if (blockIdx.x < Bc) {
    // ------------------------------ FPS ---------------------------------
    const int b = blockIdx.x;
    const float* db = data + (size_t)b * Nc * 3;

    float px[32], py[32], pz[32], dist[32];
#pragma unroll
    for (int j = 0; j < 32; ++j) {
      int p = t + 256 * j;
      px[j] = db[p * 3 + 0];
      py[j] = db[p * 3 + 1];
      pz[j] = db[p * 3 + 2];
      dist[j] = 1e10f;
      lx[p] = px[j]; ly[p] = py[j]; lz[p] = pz[j];
    }
    __syncthreads();

    int far = 0;
    for (int it = 0; it < Sc; ++it) {
      const int sfar = __builtin_amdgcn_readfirstlane(far);
      if (t == 0) {
        idx_hist[it] = sfar;
        atomicExch(&idx_pub[(b << 9) + it], sfar);  // publish, fire-and-forget
      }
      const float cx = lx[sfar];
      const float cy = ly[sfar];
      const float cz = lz[sfar];

      float best = -1.0f; int bj = 0;
#pragma unroll
      for (int j = 0; j < 32; ++j) {
        float dx = __fsub_rn(px[j], cx);
        float dy = __fsub_rn(py[j], cy);
        float dz = __fsub_rn(pz[j], cz);
        float d = __fadd_rn(__fadd_rn(__fmul_rn(dx, dx), __fmul_rn(dy, dy)),
                            __fmul_rn(dz, dz));
        float nd = fminf(dist[j], d);
        dist[j] = nd;
        if (nd > best) { best = nd; bj = j; }  // strict >: first index in lane
      }
      const int bidx = t + 256 * bj;

      float wmax = best;
      wmax = dpp_max_stage<0xB1>(wmax);   // quad_perm [1,0,3,2]
      wmax = dpp_max_stage<0x4E>(wmax);   // quad_perm [2,3,0,1]
      wmax = dpp_max_stage<0x141>(wmax);  // row_half_mirror
      wmax = dpp_max_stage<0x140>(wmax);  // row_mirror
      wmax = fmaxf(wmax, __shfl_xor(wmax, 16));
      wmax = fmaxf(wmax, __shfl_xor(wmax, 32));

      unsigned long long m = __ballot(best == wmax);
      int idx;
      if (__popcll(m) == 1) {
        idx = __shfl(bidx, (int)__ffsll((long long)m) - 1);
      } else {
        int cand = (best == wmax) ? bidx : 0x7fffffff;
#pragma unroll
        for (int off = 32; off; off >>= 1) cand = min(cand, __shfl_xor(cand, off));
        idx = cand;
      }

      unsigned long long key =
          ((unsigned long long)__float_as_uint(wmax) << 32) |
          (unsigned long long)(0xFFFFFFFFu - (unsigned)idx);
      const int par = it & 1;
      if (lane == 0) red_k[par][w] = key;
      __syncthreads();

      unsigned long long k0 = red_k[par][0];
      unsigned long long k1 = red_k[par][1];
      unsigned long long k2 = red_k[par][2];
      unsigned long long k3 = red_k[par][3];
      unsigned long long ka = (k0 > k1) ? k0 : k1;
      unsigned long long kb = (k2 > k3) ? k2 : k3;
      unsigned long long kk = (ka > kb) ? ka : kb;
      far = (int)(0xFFFFFFFFu - (unsigned)(kk & 0xFFFFFFFFull));
    }

    __syncthreads();
    for (int s = t; s < Sc; s += 256) {
      int id = idx_hist[s];
      size_t o = ((size_t)b * Sc + s) * 3;
      cent_out[o + 0] = lx[id];
      cent_out[o + 1] = ly[id];
      cent_out[o + 2] = lz[id];
    }
  } else {
    // --------------------------- ball query ------------------------------
    const int wid = (blockIdx.x - Bc) * 4 + w;   // 0..959
    const int bb = wid & 15;                     // batch (batch-isolated wave)
    const int u  = wid >> 4;                     // 0..59
    const float* db = data + (size_t)bb * Nc * 3;
    const float* fb = feat + (size_t)bb * Nc * 3;

    float W[6];
#pragma unroll
    for (int c = 0; c < 6; ++c) W[c] = w0[lane * 6 + c];
    const float bias = b0[lane];
    float sum = 0.f, sq = 0.f;

    for (int s = u; s < Sc; s += 60) {
      const int q = bb * Sc + s;

      // prefetch chunk 0 while (possibly) waiting for the centroid index
      float px = db[lane * 3 + 0];
      float py = db[lane * 3 + 1];
      float pz = db[lane * 3 + 2];

      int ci;
      for (;;) {
        int t0 = -1;
        if (lane == 0) t0 = atomicAdd(&idx_pub[q], 0);  // coherent RMW read
        ci = __shfl(t0, 0);
        if (ci >= 0) break;
        __builtin_amdgcn_s_sleep(32);   // ~2k cycles between polls
      }

      const float qx = db[ci * 3 + 0];
      const float qy = db[ci * 3 + 1];
      const float qz = db[ci * 3 + 2];
      const float q2 = __fadd_rn(__fadd_rn(__fmul_rn(qx, qx), __fmul_rn(qy, qy)),
                                 __fmul_rn(qz, qz));

      int have = 0;
      for (int base = 0; base < Nc; base += 64) {
        // software pipeline: issue next chunk's loads before the ballot/break
        const int inext = (base + 64 + lane) & (Nc - 1);
        float nx = db[inext * 3 + 0];
        float ny = db[inext * 3 + 1];
        float nz = db[inext * 3 + 2];

        float p2 = __fadd_rn(__fadd_rn(__fmul_rn(px, px), __fmul_rn(py, py)),
                             __fmul_rn(pz, pz));
        float dt = fmaf(qz, pz, fmaf(qy, py, __fmul_rn(qx, px)));
        float d = __fadd_rn(__fadd_rn(__fmul_rn(-2.0f, dt), q2), p2);
        bool ok = d <= 0.16f;
        unsigned long long mask = __ballot(ok);
        if (mask) {
          int pos = have + __popcll(mask & ((1ull << lane) - 1ull));
          if (ok && pos < Kc) nbr[w][pos] = base + lane;
          have += __popcll(mask);
          if (have >= Kc) break;
        }
        px = nx; py = ny; pz = nz;
      }
      if (have > Kc) have = Kc;

      // gather + x0 write (wave-local; compiler orders ds_write -> ds_read)
      if (lane < Kc) {
        int j = nbr[w][lane < have ? lane : 0];
        float sx = __fsub_rn(db[j * 3 + 0], qx);
        float sy = __fsub_rn(db[j * 3 + 1], qy);
        float sz = __fsub_rn(db[j * 3 + 2], qz);
        float fx = fb[j * 3 + 0], fy = fb[j * 3 + 1], fz = fb[j * 3 + 2];
        size_t pidx = (size_t)q * Kc + lane;
        x0[(size_t)0 * Pc + pidx] = sx;
        x0[(size_t)1 * Pc + pidx] = sy;
        x0[(size_t)2 * Pc + pidx] = sz;
        x0[(size_t)3 * Pc + pidx] = fx;
        x0[(size_t)4 * Pc + pidx] = fy;
        x0[(size_t)5 * Pc + pidx] = fz;
        x0s[w][0][lane] = sx; x0s[w][1][lane] = sy; x0s[w][2][lane] = sz;
        x0s[w][3][lane] = fx; x0s[w][4][lane] = fy; x0s[w][5][lane] = fz;
      }

      // y0 = conv0(x0)+b0 partial stats: lane = channel, broadcast LDS reads
#pragma unroll 4
      for (int k = 0; k < Kc; ++k) {
        float y = bias;
#pragma unroll
        for (int c = 0; c < 6; ++c) y = fmaf(x0s[w][c][k], W[c], y);
        sum += y;
        sq = fmaf(y, y, sq);
      }
    }
    part0[(size_t)wid * 128 + lane] = sum;
    part0[(size_t)wid * 128 + 64 + lane] = sq;
  }
}

// One block per channel; 256-thread fixed-order tree (deterministic, double).
__global__ __launch_bounds__(256)
void reduce_k(const float* __restrict__ part, int nblk, int nch,
              const float* __restrict__ g, const float* __restrict__ be,
              float* __restrict__ AB) {
  const int o = blockIdx.x;
  const int t = threadIdx.x;
  double sum = 0.0, sq = 0.0;
  for (int i = t; i < nblk; i += 256) {
    sum += (double)part[(size_t)i * (2 * nch) + o];
    sq  += (double)part[(size_t)i * (2 * nch) + nch + o];
  }
  __shared__ double ls[256], lq[256];
  ls[t] = sum; lq[t] = sq;
  __syncthreads();
  for (int s = 128; s > 0; s >>= 1) {
    if (t < s) { ls[t] += ls[t + s]; lq[t] += lq[t + s]; }
    __syncthreads();
  }
  if (t == 0) {
    double m = ls[0] / (double)Pc;
    double v = lq[0] / (double)Pc - m * m;
    double A = (double)g[o] / sqrt(v + 1e-5);
    AB[o] = (float)A;
    AB[nch + o] = (float)((double)be[o] - m * A);
  }
}

// reduce layer-2 stats fused with the final affine+relu epilogue.
__global__ __launch_bounds__(256)
void reduce2_final_k(const float* __restrict__ part, int nblk,
                     const float* __restrict__ g, const float* __restrict__ be,
                     const float* __restrict__ maxy2,
                     float* __restrict__ out) {
  const int o = blockIdx.x;          // 0..127
  const int t = threadIdx.x;
  double sum = 0.0, sq = 0.0;
  for (int i = t; i < nblk; i += 256) {
    sum += (double)part[(size_t)i * 256 + o];
    sq  += (double)part[(size_t)i * 256 + 128 + o];
  }
  __shared__ double ls[256], lq[256];
  ls[t] = sum; lq[t] = sq;
  __syncthreads();
  for (int s = 128; s > 0; s >>= 1) {
    if (t < s) { ls[t] += ls[t + s]; lq[t] += lq[t + s]; }
    __syncthreads();
  }
  __shared__ float sA, sB;
  if (t == 0) {
    double m = ls[0] / (double)Pc;
    double v = lq[0] / (double)Pc - m * m;
    double A = (double)g[o] / sqrt(v + 1e-5);
    sA = (float)A;
    sB = (float)((double)be[o] - m * A);
  }
  __syncthreads();
  const float A = sA, B = sB;
  for (int grp = t; grp < Bc * Sc; grp += 256) {
    float v = maxy2[(size_t)grp * 128 + o];
    out[(size_t)grp * 128 + o] = fmaxf(fmaf(v, A, B), 0.f);
  }
}

// ---------------------------------------------------------------------------
// pass_b (r22): 2-way o-interleave (r11, +21us confirmed) + NP=2 point
// blocking + per-wave o-rotation. Mechanism (r10/r11 confirmed): per-o
// wave-uniform weight fetch costs a ~500-600cy scalar/L2 drain; levers are
// (a) more FMA work per drain (NP=2 doubles it, halves total drains) and
// (b) desynchronizing the 4 lockstep waves (rotation: wave w starts at
// o=w*16) so one wave's FMA block covers another's drain.
// Per-(o,point) math, FP order, and store addresses untouched -> y1
// bit-identical. ~180 VGPR at (256,1): no spill, 2 waves/SIMD.
// ---------------------------------------------------------------------------
__global__ __launch_bounds__(256, 1)
void pass_b(const float* __restrict__ x0, const float* __restrict__ w0,
            const float* __restrict__ b0, const float* __restrict__ AB0,
            const float* __restrict__ w1, const float* __restrict__ b1,
            float* __restrict__ y1) {
  const int t = threadIdx.x;
  const int w = t >> 6;
  const int p0 = blockIdx.x * 512 + t;     // point A
  const int p1 = p0 + 256;                 // point B

  float xinA[6], xinB[6];
#pragma unroll
  for (int c = 0; c < 6; ++c) {
    xinA[c] = x0[(size_t)c * Pc + p0];
    xinB[c] = x0[(size_t)c * Pc + p1];
  }

  v2f x1pA[32], x1pB[32];
#pragma unroll
  for (int j = 0; j < 32; ++j) {
    float ya0 = b0[2 * j];
#pragma unroll
    for (int c = 0; c < 6; ++c) ya0 = fmaf(xinA[c], w0[(2 * j) * 6 + c], ya0);
    x1pA[j].x = fmaxf(fmaf(ya0, AB0[2 * j], AB0[64 + 2 * j]), 0.f);
    float ya1 = b0[2 * j + 1];
#pragma unroll
    for (int c = 0; c < 6; ++c) ya1 = fmaf(xinA[c], w0[(2 * j + 1) * 6 + c], ya1);
    x1pA[j].y = fmaxf(fmaf(ya1, AB0[2 * j + 1], AB0[64 + 2 * j + 1]), 0.f);
    float yb0 = b0[2 * j];
#pragma unroll
    for (int c = 0; c < 6; ++c) yb0 = fmaf(xinB[c], w0[(2 * j) * 6 + c], yb0);
    x1pB[j].x = fmaxf(fmaf(yb0, AB0[2 * j], AB0[64 + 2 * j]), 0.f);
    float yb1 = b0[2 * j + 1];
#pragma unroll
    for (int c = 0; c < 6; ++c) yb1 = fmaf(xinB[c], w0[(2 * j + 1) * 6 + c], yb1);
    x1pB[j].y = fmaxf(fmaf(yb1, AB0[2 * j + 1], AB0[64 + 2 * j + 1]), 0.f);
  }

  const v2f* __restrict__ w1v = (const v2f*)w1;

  for (int oi = 0; oi < 64; oi += 2) {
    const int o = (oi + (w << 4)) & 63;    // per-wave rotation (o even)
    v2f aA01; aA01.x = b1[o];     aA01.y = 0.f;
    v2f aA23; aA23.x = 0.f;       aA23.y = 0.f;
    v2f cA01; cA01.x = b1[o + 1]; cA01.y = 0.f;
    v2f cA23; cA23.x = 0.f;       cA23.y = 0.f;
    v2f aB01; aB01.x = b1[o];     aB01.y = 0.f;
    v2f aB23; aB23.x = 0.f;       aB23.y = 0.f;
    v2f cB01; cB01.x = b1[o + 1]; cB01.y = 0.f;
    v2f cB23; cB23.x = 0.f;       cB23.y = 0.f;
#pragma unroll
    for (int c2 = 0; c2 < 32; c2 += 2) {
      v2f wa0 = w1v[o * 32 + c2 + 0];
      v2f wa1 = w1v[o * 32 + c2 + 1];
      v2f wc0 = w1v[(o + 1) * 32 + c2 + 0];
      v2f wc1 = w1v[(o + 1) * 32 + c2 + 1];
      aA01 = PKFMA(x1pA[c2 + 0], wa0, aA01);
      aA23 = PKFMA(x1pA[c2 + 1], wa1, aA23);
      cA01 = PKFMA(x1pA[c2 + 0], wc0, cA01);
      cA23 = PKFMA(x1pA[c2 + 1], wc1, cA23);
      aB01 = PKFMA(x1pB[c2 + 0], wa0, aB01);
      aB23 = PKFMA(x1pB[c2 + 1], wa1, aB23);
      cB01 = PKFMA(x1pB[c2 + 0], wc0, cB01);
      cB23 = PKFMA(x1pB[c2 + 1], wc1, cB23);
    }
    y1[(size_t)o * Pc + p0]       = (aA01.x + aA01.y) + (aA23.x + aA23.y);
    y1[(size_t)o * Pc + p1]       = (aB01.x + aB01.y) + (aB23.x + aB23.y);
    y1[(size_t)(o + 1) * Pc + p0] = (cA01.x + cA01.y) + (cA23.x + cA23.y);
    y1[(size_t)(o + 1) * Pc + p1] = (cB01.x + cB01.y) + (cB23.x + cB23.y);
  }
}

// stats1_k: per-channel sum/sumsq partials from the y1 planes (r9 form).
__global__ __launch_bounds__(256)
void stats1_k(const float* __restrict__ y1, float* __restrict__ pair1) {
  const int b = blockIdx.x;
  const int o = b >> 4, seg = b & 15;
  const int t = threadIdx.x;
  const float* plane = y1 + (size_t)o * Pc + (size_t)seg * 16384;
  float sum = 0.f, sq = 0.f;
  for (int i = t; i < 16384; i += 256) {
    float v = plane[i];
    sum += v;
    sq = fmaf(v, v, sq);
  }
  __shared__ float ls[256], lq[256];
  ls[t] = sum; lq[t] = sq;
  __syncthreads();
  for (int s = 128; s > 0; s >>= 1) {
    if (t < s) { ls[t] += ls[t + s]; lq[t] += lq[t + s]; }
    __syncthreads();
  }
  if (t == 0) {
    pair1[(size_t)b * 2 + 0] = ls[0];
    pair1[(size_t)b * 2 + 1] = lq[0];
  }
}

// Tiny deterministic double reduce over the 16 segment pairs per channel.
__global__ __launch_bounds__(64)
void reduceAB_pairs_k(const float* __restrict__ pair, int nseg,
                      const float* __restrict__ g, const float* __restrict__ be,
                      float* __restrict__ AB, int nch) {
  const int o = blockIdx.x;
  if (threadIdx.x == 0) {
    double sum = 0.0, sq = 0.0;
    for (int s = 0; s < nseg; ++s) {
      sum += (double)pair[(size_t)(o * nseg + s) * 2 + 0];
      sq  += (double)pair[(size_t)(o * nseg + s) * 2 + 1];
    }
    double m = sum / (double)Pc;
    double v = sq / (double)Pc - m * m;
    double A = (double)g[o] / sqrt(v + 1e-5);
    AB[o] = (float)A;
    AB[nch + o] = (float)((double)be[o] - m * A);
  }
}

// ---------------------------------------------------------------------------
// pass_c (r22): 2-way o-interleave + NP=2 point blocking + per-wave
// o-rotation (wave w starts at o=w*32). Per-o conv math, maxy2 shfl-tree,
// FP order unchanged -> maxy2 bit-identical. Stats: svA+svB combined into
// one partial (grouping change only, absorbed by double reduce; nblk=512).
// ---------------------------------------------------------------------------
__global__ __launch_bounds__(256, 1)
void pass_c(const float* __restrict__ y1, const float* __restrict__ AB1,
            const float* __restrict__ w2, const float* __restrict__ b2,
            float* __restrict__ maxy2, float* __restrict__ part2) {
  const int t = threadIdx.x;
  const int lane = t & 63, w = t >> 6;
  const int p0 = blockIdx.x * 512 + t;     // point A
  const int p1 = p0 + 256;                 // point B
  const int grp0 = p0 >> 5, grp1 = p1 >> 5;

  v2f x2pA[32], x2pB[32];
#pragma unroll
  for (int c = 0; c < 64; c += 2) {
    float vA0 = y1[(size_t)c * Pc + p0];
    float vA1 = y1[(size_t)(c + 1) * Pc + p0];
    x2pA[c >> 1].x = fmaxf(fmaf(vA0, AB1[c], AB1[64 + c]), 0.f);
    x2pA[c >> 1].y = fmaxf(fmaf(vA1, AB1[c + 1], AB1[64 + c + 1]), 0.f);
    float vB0 = y1[(size_t)c * Pc + p1];
    float vB1 = y1[(size_t)(c + 1) * Pc + p1];
    x2pB[c >> 1].x = fmaxf(fmaf(vB0, AB1[c], AB1[64 + c]), 0.f);
    x2pB[c >> 1].y = fmaxf(fmaf(vB1, AB1[c + 1], AB1[64 + c + 1]), 0.f);
  }

  const v2f* __restrict__ w2v = (const v2f*)w2;

  __shared__ float ssum[4][128][9], ssq[4][128][9];  // padded: stride 9

  for (int oi = 0; oi < 128; oi += 2) {
    const int o = (oi + (w << 5)) & 127;   // per-wave rotation (o even)
    v2f aA01; aA01.x = b2[o];     aA01.y = 0.f;
    v2f aA23; aA23.x = 0.f;       aA23.y = 0.f;
    v2f cA01; cA01.x = b2[o + 1]; cA01.y = 0.f;
    v2f cA23; cA23.x = 0.f;       cA23.y = 0.f;
    v2f aB01; aB01.x = b2[o];     aB01.y = 0.f;
    v2f aB23; aB23.x = 0.f;       aB23.y = 0.f;
    v2f cB01; cB01.x = b2[o + 1]; cB01.y = 0.f;
    v2f cB23; cB23.x = 0.f;       cB23.y = 0.f;
#pragma unroll
    for (int c2 = 0; c2 < 32; c2 += 2) {
      v2f wa0 = w2v[o * 32 + c2 + 0];
      v2f wa1 = w2v[o * 32 + c2 + 1];
      v2f wc0 = w2v[(o + 1) * 32 + c2 + 0];
      v2f wc1 = w2v[(o + 1) * 32 + c2 + 1];
      aA01 = PKFMA(x2pA[c2 + 0], wa0, aA01);
      aA23 = PKFMA(x2pA[c2 + 1], wa1, aA23);
      cA01 = PKFMA(x2pA[c2 + 0], wc0, cA01);
      cA23 = PKFMA(x2pA[c2 + 1], wc1, cA23);
      aB01 = PKFMA(x2pB[c2 + 0], wa0, aB01);
      aB23 = PKFMA(x2pB[c2 + 1], wa1, aB23);
      cB01 = PKFMA(x2pB[c2 + 0], wc0, cB01);
      cB23 = PKFMA(x2pB[c2 + 1], wc1, cB23);
    }
    float accA0 = (aA01.x + aA01.y) + (aA23.x + aA23.y);  // (o,   pA)
    float accA1 = (cA01.x + cA01.y) + (cA23.x + cA23.y);  // (o+1, pA)
    float accB0 = (aB01.x + aB01.y) + (aB23.x + aB23.y);  // (o,   pB)
    float accB1 = (cB01.x + cB01.y) + (cB23.x + cB23.y);  // (o+1, pB)

    // maxy2: identical shfl tree per (o, point-set)
    {
      float mx = accA0;
#pragma unroll
      for (int off = 16; off > 0; off >>= 1) mx = fmaxf(mx, __shfl_xor(mx, off));
      if ((lane & 31) == 0) maxy2[(size_t)grp0 * 128 + o] = mx;
    }
    {
      float mx = accA1;
#pragma unroll
      for (int off = 16; off > 0; off >>= 1) mx = fmaxf(mx, __shfl_xor(mx, off));
      if ((lane & 31) == 0) maxy2[(size_t)grp0 * 128 + o + 1] = mx;
    }
    {
      float mx = accB0;
#pragma unroll
      for (int off = 16; off > 0; off >>= 1) mx = fmaxf(mx, __shfl_xor(mx, off));
      if ((lane & 31) == 0) maxy2[(size_t)grp1 * 128 + o] = mx;
    }
    {
      float mx = accB1;
#pragma unroll
      for (int off = 16; off > 0; off >>= 1) mx = fmaxf(mx, __shfl_xor(mx, off));
      if ((lane & 31) == 0) maxy2[(size_t)grp1 * 128 + o + 1] = mx;
    }

    // stats: A+B combined into one partial (grouping change only)
    {
      float sv = accA0 + __shfl_xor(accA0, 1);
      sv += __shfl_xor(sv, 2);
      sv += __shfl_xor(sv, 4);
      float sw = accB0 + __shfl_xor(accB0, 1);
      sw += __shfl_xor(sw, 2);
      sw += __shfl_xor(sw, 4);
      float q = accA0 * accA0;
      float qv = q + __shfl_xor(q, 1);
      qv += __shfl_xor(qv, 2);
      qv += __shfl_xor(qv, 4);
      float r = accB0 * accB0;
      float qw = r + __shfl_xor(r, 1);
      qw += __shfl_xor(qw, 2);
      qw += __shfl_xor(qw, 4);
      if ((lane & 7) == 0) {
        ssum[w][o][lane >> 3] = sv + sw;
        ssq[w][o][lane >> 3] = qv + qw;
      }
    }
    {
      float sv = accA1 + __shfl_xor(accA1, 1);
      sv += __shfl_xor(sv, 2);
      sv += __shfl_xor(sv, 4);
      float sw = accB1 + __shfl_xor(accB1, 1);
      sw += __shfl_xor(sw, 2);
      sw += __shfl_xor(sw, 4);
      float q = accA1 * accA1;
      float qv = q + __shfl_xor(q, 1);
      qv += __shfl_xor(qv, 2);
      qv += __shfl_xor(qv, 4);
      float r = accB1 * accB1;
      float qw = r + __shfl_xor(r, 1);
      qw += __shfl_xor(qw, 2);
      qw += __shfl_xor(qw, 4);
      if ((lane & 7) == 0) {
        ssum[w][o + 1][lane >> 3] = sv + sw;
        ssq[w][o + 1][lane >> 3] = qv + qw;
      }
    }
  }
  __syncthreads();
  {
    const int o = threadIdx.x & 127;
    const bool isq = threadIdx.x >= 128;
    float s = 0.f;
#pragma unroll
    for (int ww = 0; ww < 4; ++ww)
      for (int k = 0; k < 8; ++k)
        s += isq ? ssq[ww][o][k] : ssum[ww][o][k];
    part2[blockIdx.x * 256 + threadIdx.x] = s;
  }
}

extern "C" void kernel_launch(void* const* d_in, const int* in_sizes, int n_in,
                              void* d_out, int out_size, void* d_ws, size_t ws_size,
                              hipStream_t stream) {
  const float* data = (const float*)d_in[0];
  const float* feat = (const float*)d_in[1];
  const float* w0 = (const float*)d_in[2];
  const float* b0 = (const float*)d_in[3];
  const float* g0 = (const float*)d_in[4];
  const float* be0 = (const float*)d_in[5];
  const float* w1 = (const float*)d_in[6];
  const float* b1 = (const float*)d_in[7];
  const float* g1 = (const float*)d_in[8];
  const float* be1 = (const float*)d_in[9];
  const float* w2 = (const float*)d_in[10];
  const float* b2 = (const float*)d_in[11];
  const float* g2 = (const float*)d_in[12];
  const float* be2 = (const float*)d_in[13];
  float* out = (float*)d_out;

  float* ws = (float*)d_ws;
  int* idx_pub = (int*)ws; ws += (size_t)Bc * Sc;      // 8192 ints
  float* x0 = ws;      ws += (size_t)6 * Pc;
  float* y1 = ws;      ws += (size_t)64 * Pc;          // [ch][point] planes
  float* maxy2 = ws;   ws += (size_t)Bc * Sc * 128;
  float* part0 = ws;   ws += (size_t)NBALL_WAVES * 128;
  float* pair1 = ws;   ws += 1024 * 2;
  float* part2 = ws;   ws += 512 * 256;
  float* AB0 = ws;     ws += 128;
  float* AB1 = ws;     ws += 128;

  // re-poison the publication slots every graph replay
  hipMemsetAsync(idx_pub, 0xFF, (size_t)Bc * Sc * sizeof(int), stream);

  fps_ball_fused<<<Bc + NBALL_BLK, 256, 0, stream>>>(data, feat, w0, b0,
                                                     idx_pub, out, x0, part0);
  reduce_k<<<64, 256, 0, stream>>>(part0, NBALL_WAVES, 64, g0, be0, AB0);
  pass_b<<<Pc / 512, 256, 0, stream>>>(x0, w0, b0, AB0, w1, b1, y1);
  stats1_k<<<1024, 256, 0, stream>>>(y1, pair1);
  reduceAB_pairs_k<<<64, 64, 0, stream>>>(pair1, 16, g1, be1, AB1, 64);
  pass_c<<<Pc / 512, 256, 0, stream>>>(y1, AB1, w2, b2, maxy2, part2);
  reduce2_final_k<<<128, 256, 0, stream>>>(part2, 512, g2, be2, maxy2,
                                           out + (size_t)Bc * Sc * 3);
}

// Round 13
// 791.504 us; speedup vs baseline: 1.0648x; 1.0648x over previous
//
#include <hip/hip_runtime.h>
#include <math.h>

constexpr int Bc = 16;
constexpr int Nc = 8192;
constexpr int Sc = 512;
constexpr int Kc = 32;
constexpr int Pc = Bc * Sc * Kc; // 262144

constexpr int NBALL_BLK = 240;             // ball blocks (+16 FPS = 256 total)
constexpr int NBALL_WAVES = NBALL_BLK * 4; // 960 (60 waves per batch, stride 60)

typedef float v2f __attribute__((ext_vector_type(2)));

#if defined(__has_builtin)
#if __has_builtin(__builtin_elementwise_fma)
#define PKFMA(a, b, c) __builtin_elementwise_fma(a, b, c)
#endif
#endif
#ifndef PKFMA
__device__ __forceinline__ v2f pkfma_(v2f a, v2f b, v2f c) {
  v2f r; r.x = fmaf(a.x, b.x, c.x); r.y = fmaf(a.y, b.y, c.y); return r;
}
#define PKFMA(a, b, c) pkfma_(a, b, c)
#endif

// DPP-assisted wave64 max stage (ctrl is a compile-time constant)
template <int CTRL>
__device__ __forceinline__ float dpp_max_stage(float x) {
  int p = __builtin_amdgcn_update_dpp(0, __float_as_int(x), CTRL, 0xf, 0xf, true);
  return fmaxf(x, __int_as_float(p));
}

// ---------------------------------------------------------------------------
// Fused FPS + ball query producer/consumer kernel — EXACT round-0 config
// (measured 486-495us, stable across r1-r12). Do not touch.
// ---------------------------------------------------------------------------
__global__ __launch_bounds__(256, 1)
void fps_ball_fused(const float* __restrict__ data,
                    const float* __restrict__ feat,
                    const float* __restrict__ w0,
                    const float* __restrict__ b0,
                    int* __restrict__ idx_pub,
                    float* __restrict__ cent_out,
                    float* __restrict__ x0,
                    float* __restrict__ part0) {
  __shared__ float lx[Nc], ly[Nc], lz[Nc];          // 96 KB point mirror (FPS)
  __shared__ unsigned long long red_k[2][4];
  __shared__ int idx_hist[Sc];
  __shared__ int nbr[4][Kc];                        // per-wave (ball)
  __shared__ float x0s[4][6][Kc];                   // per-wave (ball)

  const int t = threadIdx.x;
  const int lane = t & 63, w = t >> 6;

  if (blockIdx.x < Bc) {
    // ------------------------------ FPS ---------------------------------
    const int b = blockIdx.x;
    const float* db = data + (size_t)b * Nc * 3;

    float px[32], py[32], pz[32], dist[32];
#pragma unroll
    for (int j = 0; j < 32; ++j) {
      int p = t + 256 * j;
      px[j] = db[p * 3 + 0];
      py[j] = db[p * 3 + 1];
      pz[j] = db[p * 3 + 2];
      dist[j] = 1e10f;
      lx[p] = px[j]; ly[p] = py[j]; lz[p] = pz[j];
    }
    __syncthreads();

    int far = 0;
    for (int it = 0; it < Sc; ++it) {
      const int sfar = __builtin_amdgcn_readfirstlane(far);
      if (t == 0) {
        idx_hist[it] = sfar;
        atomicExch(&idx_pub[(b << 9) + it], sfar);  // publish, fire-and-forget
      }
      const float cx = lx[sfar];
      const float cy = ly[sfar];
      const float cz = lz[sfar];

      float best = -1.0f; int bj = 0;
#pragma unroll
      for (int j = 0; j < 32; ++j) {
        float dx = __fsub_rn(px[j], cx);
        float dy = __fsub_rn(py[j], cy);
        float dz = __fsub_rn(pz[j], cz);
        float d = __fadd_rn(__fadd_rn(__fmul_rn(dx, dx), __fmul_rn(dy, dy)),
                            __fmul_rn(dz, dz));
        float nd = fminf(dist[j], d);
        dist[j] = nd;
        if (nd > best) { best = nd; bj = j; }  // strict >: first index in lane
      }
      const int bidx = t + 256 * bj;

      float wmax = best;
      wmax = dpp_max_stage<0xB1>(wmax);   // quad_perm [1,0,3,2]
      wmax = dpp_max_stage<0x4E>(wmax);   // quad_perm [2,3,0,1]
      wmax = dpp_max_stage<0x141>(wmax);  // row_half_mirror
      wmax = dpp_max_stage<0x140>(wmax);  // row_mirror
      wmax = fmaxf(wmax, __shfl_xor(wmax, 16));
      wmax = fmaxf(wmax, __shfl_xor(wmax, 32));

      unsigned long long m = __ballot(best == wmax);
      int idx;
      if (__popcll(m) == 1) {
        idx = __shfl(bidx, (int)__ffsll((long long)m) - 1);
      } else {
        int cand = (best == wmax) ? bidx : 0x7fffffff;
#pragma unroll
        for (int off = 32; off; off >>= 1) cand = min(cand, __shfl_xor(cand, off));
        idx = cand;
      }

      unsigned long long key =
          ((unsigned long long)__float_as_uint(wmax) << 32) |
          (unsigned long long)(0xFFFFFFFFu - (unsigned)idx);
      const int par = it & 1;
      if (lane == 0) red_k[par][w] = key;
      __syncthreads();

      unsigned long long k0 = red_k[par][0];
      unsigned long long k1 = red_k[par][1];
      unsigned long long k2 = red_k[par][2];
      unsigned long long k3 = red_k[par][3];
      unsigned long long ka = (k0 > k1) ? k0 : k1;
      unsigned long long kb = (k2 > k3) ? k2 : k3;
      unsigned long long kk = (ka > kb) ? ka : kb;
      far = (int)(0xFFFFFFFFu - (unsigned)(kk & 0xFFFFFFFFull));
    }

    __syncthreads();
    for (int s = t; s < Sc; s += 256) {
      int id = idx_hist[s];
      size_t o = ((size_t)b * Sc + s) * 3;
      cent_out[o + 0] = lx[id];
      cent_out[o + 1] = ly[id];
      cent_out[o + 2] = lz[id];
    }
  } else {
    // --------------------------- ball query ------------------------------
    const int wid = (blockIdx.x - Bc) * 4 + w;   // 0..959
    const int bb = wid & 15;                     // batch (batch-isolated wave)
    const int u  = wid >> 4;                     // 0..59
    const float* db = data + (size_t)bb * Nc * 3;
    const float* fb = feat + (size_t)bb * Nc * 3;

    float W[6];
#pragma unroll
    for (int c = 0; c < 6; ++c) W[c] = w0[lane * 6 + c];
    const float bias = b0[lane];
    float sum = 0.f, sq = 0.f;

    for (int s = u; s < Sc; s += 60) {
      const int q = bb * Sc + s;

      // prefetch chunk 0 while (possibly) waiting for the centroid index
      float px = db[lane * 3 + 0];
      float py = db[lane * 3 + 1];
      float pz = db[lane * 3 + 2];

      int ci;
      for (;;) {
        int t0 = -1;
        if (lane == 0) t0 = atomicAdd(&idx_pub[q], 0);  // coherent RMW read
        ci = __shfl(t0, 0);
        if (ci >= 0) break;
        __builtin_amdgcn_s_sleep(32);   // ~2k cycles between polls
      }

      const float qx = db[ci * 3 + 0];
      const float qy = db[ci * 3 + 1];
      const float qz = db[ci * 3 + 2];
      const float q2 = __fadd_rn(__fadd_rn(__fmul_rn(qx, qx), __fmul_rn(qy, qy)),
                                 __fmul_rn(qz, qz));

      int have = 0;
      for (int base = 0; base < Nc; base += 64) {
        // software pipeline: issue next chunk's loads before the ballot/break
        const int inext = (base + 64 + lane) & (Nc - 1);
        float nx = db[inext * 3 + 0];
        float ny = db[inext * 3 + 1];
        float nz = db[inext * 3 + 2];

        float p2 = __fadd_rn(__fadd_rn(__fmul_rn(px, px), __fmul_rn(py, py)),
                             __fmul_rn(pz, pz));
        float dt = fmaf(qz, pz, fmaf(qy, py, __fmul_rn(qx, px)));
        float d = __fadd_rn(__fadd_rn(__fmul_rn(-2.0f, dt), q2), p2);
        bool ok = d <= 0.16f;
        unsigned long long mask = __ballot(ok);
        if (mask) {
          int pos = have + __popcll(mask & ((1ull << lane) - 1ull));
          if (ok && pos < Kc) nbr[w][pos] = base + lane;
          have += __popcll(mask);
          if (have >= Kc) break;
        }
        px = nx; py = ny; pz = nz;
      }
      if (have > Kc) have = Kc;

      // gather + x0 write (wave-local; compiler orders ds_write -> ds_read)
      if (lane < Kc) {
        int j = nbr[w][lane < have ? lane : 0];
        float sx = __fsub_rn(db[j * 3 + 0], qx);
        float sy = __fsub_rn(db[j * 3 + 1], qy);
        float sz = __fsub_rn(db[j * 3 + 2], qz);
        float fx = fb[j * 3 + 0], fy = fb[j * 3 + 1], fz = fb[j * 3 + 2];
        size_t pidx = (size_t)q * Kc + lane;
        x0[(size_t)0 * Pc + pidx] = sx;
        x0[(size_t)1 * Pc + pidx] = sy;
        x0[(size_t)2 * Pc + pidx] = sz;
        x0[(size_t)3 * Pc + pidx] = fx;
        x0[(size_t)4 * Pc + pidx] = fy;
        x0[(size_t)5 * Pc + pidx] = fz;
        x0s[w][0][lane] = sx; x0s[w][1][lane] = sy; x0s[w][2][lane] = sz;
        x0s[w][3][lane] = fx; x0s[w][4][lane] = fy; x0s[w][5][lane] = fz;
      }

      // y0 = conv0(x0)+b0 partial stats: lane = channel, broadcast LDS reads
#pragma unroll 4
      for (int k = 0; k < Kc; ++k) {
        float y = bias;
#pragma unroll
        for (int c = 0; c < 6; ++c) y = fmaf(x0s[w][c][k], W[c], y);
        sum += y;
        sq = fmaf(y, y, sq);
      }
    }
    part0[(size_t)wid * 128 + lane] = sum;
    part0[(size_t)wid * 128 + 64 + lane] = sq;
  }
}

// One block per channel; 256-thread fixed-order tree (deterministic, double).
__global__ __launch_bounds__(256)
void reduce_k(const float* __restrict__ part, int nblk, int nch,
              const float* __restrict__ g, const float* __restrict__ be,
              float* __restrict__ AB) {
  const int o = blockIdx.x;
  const int t = threadIdx.x;
  double sum = 0.0, sq = 0.0;
  for (int i = t; i < nblk; i += 256) {
    sum += (double)part[(size_t)i * (2 * nch) + o];
    sq  += (double)part[(size_t)i * (2 * nch) + nch + o];
  }
  __shared__ double ls[256], lq[256];
  ls[t] = sum; lq[t] = sq;
  __syncthreads();
  for (int s = 128; s > 0; s >>= 1) {
    if (t < s) { ls[t] += ls[t + s]; lq[t] += lq[t + s]; }
    __syncthreads();
  }
  if (t == 0) {
    double m = ls[0] / (double)Pc;
    double v = lq[0] / (double)Pc - m * m;
    double A = (double)g[o] / sqrt(v + 1e-5);
    AB[o] = (float)A;
    AB[nch + o] = (float)((double)be[o] - m * A);
  }
}

// reduce layer-2 stats fused with the final affine+relu epilogue.
__global__ __launch_bounds__(256)
void reduce2_final_k(const float* __restrict__ part, int nblk,
                     const float* __restrict__ g, const float* __restrict__ be,
                     const float* __restrict__ maxy2,
                     float* __restrict__ out) {
  const int o = blockIdx.x;          // 0..127
  const int t = threadIdx.x;
  double sum = 0.0, sq = 0.0;
  for (int i = t; i < nblk; i += 256) {
    sum += (double)part[(size_t)i * 256 + o];
    sq  += (double)part[(size_t)i * 256 + 128 + o];
  }
  __shared__ double ls[256], lq[256];
  ls[t] = sum; lq[t] = sq;
  __syncthreads();
  for (int s = 128; s > 0; s >>= 1) {
    if (t < s) { ls[t] += ls[t + s]; lq[t] += lq[t + s]; }
    __syncthreads();
  }
  __shared__ float sA, sB;
  if (t == 0) {
    double m = ls[0] / (double)Pc;
    double v = lq[0] / (double)Pc - m * m;
    double A = (double)g[o] / sqrt(v + 1e-5);
    sA = (float)A;
    sB = (float)((double)be[o] - m * A);
  }
  __syncthreads();
  const float A = sA, B = sB;
  for (int grp = t; grp < Bc * Sc; grp += 256) {
    float v = maxy2[(size_t)grp * 128 + o];
    out[(size_t)grp * 128 + o] = fmaxf(fmaf(v, A, B), 0.f);
  }
}

// ---------------------------------------------------------------------------
// pass_b (r23): exact r11 structure (765.9us best) with the o-interleave
// widened 2 -> 4. r12 lesson: NP=2 point-blocking doubled the x-arrays and
// blew the register envelope (-77us); widening the interleave adds only
// accumulators (+16 VGPR) and weight temps, ~110 live regs, no spill.
// Mechanism (r10/r11 confirmed): per-o uniform weight fetch costs a long
// drain; 4 rows per drain quarters the drain count vs 1-way.
// Per-channel accumulator chains / FP order / stores identical per o ->
// y1 bit-identical.
// ---------------------------------------------------------------------------
__global__ __launch_bounds__(256, 1)
void pass_b(const float* __restrict__ x0, const float* __restrict__ w0,
            const float* __restrict__ b0, const float* __restrict__ AB0,
            const float* __restrict__ w1, const float* __restrict__ b1,
            float* __restrict__ y1) {
  const int p = blockIdx.x * 256 + threadIdx.x;

  float xin[6];
#pragma unroll
  for (int c = 0; c < 6; ++c) xin[c] = x0[(size_t)c * Pc + p];

  v2f x1p[32];
#pragma unroll
  for (int j = 0; j < 32; ++j) {
    float y0v = b0[2 * j];
#pragma unroll
    for (int c = 0; c < 6; ++c) y0v = fmaf(xin[c], w0[(2 * j) * 6 + c], y0v);
    x1p[j].x = fmaxf(fmaf(y0v, AB0[2 * j], AB0[64 + 2 * j]), 0.f);
    float y1v = b0[2 * j + 1];
#pragma unroll
    for (int c = 0; c < 6; ++c) y1v = fmaf(xin[c], w0[(2 * j + 1) * 6 + c], y1v);
    x1p[j].y = fmaxf(fmaf(y1v, AB0[2 * j + 1], AB0[64 + 2 * j + 1]), 0.f);
  }

  const v2f* __restrict__ w1v = (const v2f*)w1;

  for (int o = 0; o < 64; o += 4) {
    v2f a01; a01.x = b1[o];     a01.y = 0.f;
    v2f a23; a23.x = 0.f;       a23.y = 0.f;
    v2f c01; c01.x = b1[o + 1]; c01.y = 0.f;
    v2f c23; c23.x = 0.f;       c23.y = 0.f;
    v2f e01; e01.x = b1[o + 2]; e01.y = 0.f;
    v2f e23; e23.x = 0.f;       e23.y = 0.f;
    v2f g01; g01.x = b1[o + 3]; g01.y = 0.f;
    v2f g23; g23.x = 0.f;       g23.y = 0.f;
#pragma unroll
    for (int c2 = 0; c2 < 32; c2 += 2) {
      a01 = PKFMA(x1p[c2 + 0], w1v[o * 32 + c2 + 0], a01);
      a23 = PKFMA(x1p[c2 + 1], w1v[o * 32 + c2 + 1], a23);
      c01 = PKFMA(x1p[c2 + 0], w1v[(o + 1) * 32 + c2 + 0], c01);
      c23 = PKFMA(x1p[c2 + 1], w1v[(o + 1) * 32 + c2 + 1], c23);
      e01 = PKFMA(x1p[c2 + 0], w1v[(o + 2) * 32 + c2 + 0], e01);
      e23 = PKFMA(x1p[c2 + 1], w1v[(o + 2) * 32 + c2 + 1], e23);
      g01 = PKFMA(x1p[c2 + 0], w1v[(o + 3) * 32 + c2 + 0], g01);
      g23 = PKFMA(x1p[c2 + 1], w1v[(o + 3) * 32 + c2 + 1], g23);
    }
    y1[(size_t)o * Pc + p]       = (a01.x + a01.y) + (a23.x + a23.y);
    y1[(size_t)(o + 1) * Pc + p] = (c01.x + c01.y) + (c23.x + c23.y);
    y1[(size_t)(o + 2) * Pc + p] = (e01.x + e01.y) + (e23.x + e23.y);
    y1[(size_t)(o + 3) * Pc + p] = (g01.x + g01.y) + (g23.x + g23.y);
  }
}

// stats1_k: per-channel sum/sumsq partials from the y1 planes (r9 form).
__global__ __launch_bounds__(256)
void stats1_k(const float* __restrict__ y1, float* __restrict__ pair1) {
  const int b = blockIdx.x;
  const int o = b >> 4, seg = b & 15;
  const int t = threadIdx.x;
  const float* plane = y1 + (size_t)o * Pc + (size_t)seg * 16384;
  float sum = 0.f, sq = 0.f;
  for (int i = t; i < 16384; i += 256) {
    float v = plane[i];
    sum += v;
    sq = fmaf(v, v, sq);
  }
  __shared__ float ls[256], lq[256];
  ls[t] = sum; lq[t] = sq;
  __syncthreads();
  for (int s = 128; s > 0; s >>= 1) {
    if (t < s) { ls[t] += ls[t + s]; lq[t] += lq[t + s]; }
    __syncthreads();
  }
  if (t == 0) {
    pair1[(size_t)b * 2 + 0] = ls[0];
    pair1[(size_t)b * 2 + 1] = lq[0];
  }
}

// Tiny deterministic double reduce over the 16 segment pairs per channel.
__global__ __launch_bounds__(64)
void reduceAB_pairs_k(const float* __restrict__ pair, int nseg,
                      const float* __restrict__ g, const float* __restrict__ be,
                      float* __restrict__ AB, int nch) {
  const int o = blockIdx.x;
  if (threadIdx.x == 0) {
    double sum = 0.0, sq = 0.0;
    for (int s = 0; s < nseg; ++s) {
      sum += (double)pair[(size_t)(o * nseg + s) * 2 + 0];
      sq  += (double)pair[(size_t)(o * nseg + s) * 2 + 1];
    }
    double m = sum / (double)Pc;
    double v = sq / (double)Pc - m * m;
    double A = (double)g[o] / sqrt(v + 1e-5);
    AB[o] = (float)A;
    AB[nch + o] = (float)((double)be[o] - m * A);
  }
}

// ---------------------------------------------------------------------------
// pass_c (r23): exact r11 structure with the o-interleave widened 2 -> 4.
// Per-o conv math, maxy2 shfl-tree, stats epilogues, FP order unchanged
// per o -> maxy2/part2 bit-identical to r11.
// ---------------------------------------------------------------------------
__global__ __launch_bounds__(256, 1)
void pass_c(const float* __restrict__ y1, const float* __restrict__ AB1,
            const float* __restrict__ w2, const float* __restrict__ b2,
            float* __restrict__ maxy2, float* __restrict__ part2) {
  const int p = blockIdx.x * 256 + threadIdx.x;
  const int lane = threadIdx.x & 63, w = threadIdx.x >> 6;
  const int grp = p >> 5;

  v2f x2p[32];
#pragma unroll
  for (int c = 0; c < 64; c += 2) {
    float v0 = y1[(size_t)c * Pc + p];
    float v1 = y1[(size_t)(c + 1) * Pc + p];
    x2p[c >> 1].x = fmaxf(fmaf(v0, AB1[c], AB1[64 + c]), 0.f);
    x2p[c >> 1].y = fmaxf(fmaf(v1, AB1[c + 1], AB1[64 + c + 1]), 0.f);
  }

  const v2f* __restrict__ w2v = (const v2f*)w2;

  __shared__ float ssum[4][128][9], ssq[4][128][9];  // padded: stride 9

  for (int o = 0; o < 128; o += 4) {
    v2f a01; a01.x = b2[o];     a01.y = 0.f;
    v2f a23; a23.x = 0.f;       a23.y = 0.f;
    v2f c01; c01.x = b2[o + 1]; c01.y = 0.f;
    v2f c23; c23.x = 0.f;       c23.y = 0.f;
    v2f e01; e01.x = b2[o + 2]; e01.y = 0.f;
    v2f e23; e23.x = 0.f;       e23.y = 0.f;
    v2f g01; g01.x = b2[o + 3]; g01.y = 0.f;
    v2f g23; g23.x = 0.f;       g23.y = 0.f;
#pragma unroll
    for (int c2 = 0; c2 < 32; c2 += 2) {
      a01 = PKFMA(x2p[c2 + 0], w2v[o * 32 + c2 + 0], a01);
      a23 = PKFMA(x2p[c2 + 1], w2v[o * 32 + c2 + 1], a23);
      c01 = PKFMA(x2p[c2 + 0], w2v[(o + 1) * 32 + c2 + 0], c01);
      c23 = PKFMA(x2p[c2 + 1], w2v[(o + 1) * 32 + c2 + 1], c23);
      e01 = PKFMA(x2p[c2 + 0], w2v[(o + 2) * 32 + c2 + 0], e01);
      e23 = PKFMA(x2p[c2 + 1], w2v[(o + 2) * 32 + c2 + 1], e23);
      g01 = PKFMA(x2p[c2 + 0], w2v[(o + 3) * 32 + c2 + 0], g01);
      g23 = PKFMA(x2p[c2 + 1], w2v[(o + 3) * 32 + c2 + 1], g23);
    }
    float acc0 = (a01.x + a01.y) + (a23.x + a23.y);
    float acc1 = (c01.x + c01.y) + (c23.x + c23.y);
    float acc2 = (e01.x + e01.y) + (e23.x + e23.y);
    float acc3 = (g01.x + g01.y) + (g23.x + g23.y);

#pragma unroll
    for (int k = 0; k < 4; ++k) {
      float acc = (k == 0) ? acc0 : (k == 1) ? acc1 : (k == 2) ? acc2 : acc3;
      const int oc = o + k;
      float mx = acc;
#pragma unroll
      for (int off = 16; off > 0; off >>= 1) mx = fmaxf(mx, __shfl_xor(mx, off));
      if ((lane & 31) == 0) maxy2[(size_t)grp * 128 + oc] = mx;

      float sv = acc + __shfl_xor(acc, 1);
      sv += __shfl_xor(sv, 2);
      sv += __shfl_xor(sv, 4);
      float q = acc * acc;
      float qv = q + __shfl_xor(q, 1);
      qv += __shfl_xor(qv, 2);
      qv += __shfl_xor(qv, 4);
      if ((lane & 7) == 0) {
        ssum[w][oc][lane >> 3] = sv;
        ssq[w][oc][lane >> 3] = qv;
      }
    }
  }
  __syncthreads();
  {
    const int o = threadIdx.x & 127;
    const bool isq = threadIdx.x >= 128;
    float s = 0.f;
#pragma unroll
    for (int ww = 0; ww < 4; ++ww)
      for (int k = 0; k < 8; ++k)
        s += isq ? ssq[ww][o][k] : ssum[ww][o][k];
    part2[blockIdx.x * 256 + threadIdx.x] = s;
  }
}

extern "C" void kernel_launch(void* const* d_in, const int* in_sizes, int n_in,
                              void* d_out, int out_size, void* d_ws, size_t ws_size,
                              hipStream_t stream) {
  const float* data = (const float*)d_in[0];
  const float* feat = (const float*)d_in[1];
  const float* w0 = (const float*)d_in[2];
  const float* b0 = (const float*)d_in[3];
  const float* g0 = (const float*)d_in[4];
  const float* be0 = (const float*)d_in[5];
  const float* w1 = (const float*)d_in[6];
  const float* b1 = (const float*)d_in[7];
  const float* g1 = (const float*)d_in[8];
  const float* be1 = (const float*)d_in[9];
  const float* w2 = (const float*)d_in[10];
  const float* b2 = (const float*)d_in[11];
  const float* g2 = (const float*)d_in[12];
  const float* be2 = (const float*)d_in[13];
  float* out = (float*)d_out;

  float* ws = (float*)d_ws;
  int* idx_pub = (int*)ws; ws += (size_t)Bc * Sc;      // 8192 ints
  float* x0 = ws;      ws += (size_t)6 * Pc;
  float* y1 = ws;      ws += (size_t)64 * Pc;          // [ch][point] planes
  float* maxy2 = ws;   ws += (size_t)Bc * Sc * 128;
  float* part0 = ws;   ws += (size_t)NBALL_WAVES * 128;
  float* pair1 = ws;   ws += 1024 * 2;
  float* part2 = ws;   ws += 1024 * 256;
  float* AB0 = ws;     ws += 128;
  float* AB1 = ws;     ws += 128;

  // re-poison the publication slots every graph replay
  hipMemsetAsync(idx_pub, 0xFF, (size_t)Bc * Sc * sizeof(int), stream);

  fps_ball_fused<<<Bc + NBALL_BLK, 256, 0, stream>>>(data, feat, w0, b0,
                                                     idx_pub, out, x0, part0);
  reduce_k<<<64, 256, 0, stream>>>(part0, NBALL_WAVES, 64, g0, be0, AB0);
  pass_b<<<Pc / 256, 256, 0, stream>>>(x0, w0, b0, AB0, w1, b1, y1);
  stats1_k<<<1024, 256, 0, stream>>>(y1, pair1);
  reduceAB_pairs_k<<<64, 64, 0, stream>>>(pair1, 16, g1, be1, AB1, 64);
  pass_c<<<Pc / 256, 256, 0, stream>>>(y1, AB1, w2, b2, maxy2, part2);
  reduce2_final_k<<<128, 256, 0, stream>>>(part2, 1024, g2, be2, maxy2,
                                           out + (size_t)Bc * Sc * 3);
}

// Round 14
// 737.369 us; speedup vs baseline: 1.1430x; 1.0734x over previous
//
#include <hip/hip_runtime.h>
#include <math.h>

constexpr int Bc = 16;
constexpr int Nc = 8192;
constexpr int Sc = 512;
constexpr int Kc = 32;
constexpr int Pc = Bc * Sc * Kc; // 262144

constexpr int NBALL_BLK = 240;             // ball blocks (+16 FPS = 256 total)
constexpr int NBALL_WAVES = NBALL_BLK * 4; // 960 (60 waves per batch, stride 60)

typedef float v2f __attribute__((ext_vector_type(2)));

#if defined(__has_builtin)
#if __has_builtin(__builtin_elementwise_fma)
#define PKFMA(a, b, c) __builtin_elementwise_fma(a, b, c)
#endif
#endif
#ifndef PKFMA
__device__ __forceinline__ v2f pkfma_(v2f a, v2f b, v2f c) {
  v2f r; r.x = fmaf(a.x, b.x, c.x); r.y = fmaf(a.y, b.y, c.y); return r;
}
#define PKFMA(a, b, c) pkfma_(a, b, c)
#endif

// DPP-assisted wave64 max stage (ctrl is a compile-time constant)
template <int CTRL>
__device__ __forceinline__ float dpp_max_stage(float x) {
  int p = __builtin_amdgcn_update_dpp(0, __float_as_int(x), CTRL, 0xf, 0xf, true);
  return fmaxf(x, __int_as_float(p));
}

// ---------------------------------------------------------------------------
// Fused FPS + ball query kernel. FPS side untouched (r11-exact). Ball side
// (r14): scan loop made BRANCHLESS — no break, no if(mask). Semantics are
// bit-identical (once have>=Kc, pos>=Kc suppresses writes; popcll(0)=0), but
// the fixed trip count removes the ballot->branch serialization so the 128
// chunk-loads pipeline instead of issuing at L2 latency. Targets the ~41us
// post-FPS tail (fused 488 vs FPS-alone 447) — read directly off top-5.
// ---------------------------------------------------------------------------
__global__ __launch_bounds__(256, 1)
void fps_ball_fused(const float* __restrict__ data,
                    const float* __restrict__ feat,
                    const float* __restrict__ w0,
                    const float* __restrict__ b0,
                    int* __restrict__ idx_pub,
                    float* __restrict__ cent_out,
                    float* __restrict__ x0,
                    float* __restrict__ part0) {
  __shared__ float lx[Nc], ly[Nc], lz[Nc];          // 96 KB point mirror (FPS)
  __shared__ unsigned long long red_k[2][4];
  __shared__ int idx_hist[Sc];
  __shared__ int nbr[4][Kc];                        // per-wave (ball)
  __shared__ float x0s[4][6][Kc];                   // per-wave (ball)

  const int t = threadIdx.x;
  const int lane = t & 63, w = t >> 6;

  if (blockIdx.x < Bc) {
    // ------------------------------ FPS ---------------------------------
    const int b = blockIdx.x;
    const float* db = data + (size_t)b * Nc * 3;

    float px[32], py[32], pz[32], dist[32];
#pragma unroll
    for (int j = 0; j < 32; ++j) {
      int p = t + 256 * j;
      px[j] = db[p * 3 + 0];
      py[j] = db[p * 3 + 1];
      pz[j] = db[p * 3 + 2];
      dist[j] = 1e10f;
      lx[p] = px[j]; ly[p] = py[j]; lz[p] = pz[j];
    }
    __syncthreads();

    int far = 0;
    for (int it = 0; it < Sc; ++it) {
      const int sfar = __builtin_amdgcn_readfirstlane(far);
      if (t == 0) {
        idx_hist[it] = sfar;
        atomicExch(&idx_pub[(b << 9) + it], sfar);  // publish, fire-and-forget
      }
      const float cx = lx[sfar];
      const float cy = ly[sfar];
      const float cz = lz[sfar];

      float best = -1.0f; int bj = 0;
#pragma unroll
      for (int j = 0; j < 32; ++j) {
        float dx = __fsub_rn(px[j], cx);
        float dy = __fsub_rn(py[j], cy);
        float dz = __fsub_rn(pz[j], cz);
        float d = __fadd_rn(__fadd_rn(__fmul_rn(dx, dx), __fmul_rn(dy, dy)),
                            __fmul_rn(dz, dz));
        float nd = fminf(dist[j], d);
        dist[j] = nd;
        if (nd > best) { best = nd; bj = j; }  // strict >: first index in lane
      }
      const int bidx = t + 256 * bj;

      float wmax = best;
      wmax = dpp_max_stage<0xB1>(wmax);   // quad_perm [1,0,3,2]
      wmax = dpp_max_stage<0x4E>(wmax);   // quad_perm [2,3,0,1]
      wmax = dpp_max_stage<0x141>(wmax);  // row_half_mirror
      wmax = dpp_max_stage<0x140>(wmax);  // row_mirror
      wmax = fmaxf(wmax, __shfl_xor(wmax, 16));
      wmax = fmaxf(wmax, __shfl_xor(wmax, 32));

      unsigned long long m = __ballot(best == wmax);
      int idx;
      if (__popcll(m) == 1) {
        idx = __shfl(bidx, (int)__ffsll((long long)m) - 1);
      } else {
        int cand = (best == wmax) ? bidx : 0x7fffffff;
#pragma unroll
        for (int off = 32; off; off >>= 1) cand = min(cand, __shfl_xor(cand, off));
        idx = cand;
      }

      unsigned long long key =
          ((unsigned long long)__float_as_uint(wmax) << 32) |
          (unsigned long long)(0xFFFFFFFFu - (unsigned)idx);
      const int par = it & 1;
      if (lane == 0) red_k[par][w] = key;
      __syncthreads();

      unsigned long long k0 = red_k[par][0];
      unsigned long long k1 = red_k[par][1];
      unsigned long long k2 = red_k[par][2];
      unsigned long long k3 = red_k[par][3];
      unsigned long long ka = (k0 > k1) ? k0 : k1;
      unsigned long long kb = (k2 > k3) ? k2 : k3;
      unsigned long long kk = (ka > kb) ? ka : kb;
      far = (int)(0xFFFFFFFFu - (unsigned)(kk & 0xFFFFFFFFull));
    }

    __syncthreads();
    for (int s = t; s < Sc; s += 256) {
      int id = idx_hist[s];
      size_t o = ((size_t)b * Sc + s) * 3;
      cent_out[o + 0] = lx[id];
      cent_out[o + 1] = ly[id];
      cent_out[o + 2] = lz[id];
    }
  } else {
    // --------------------------- ball query ------------------------------
    const int wid = (blockIdx.x - Bc) * 4 + w;   // 0..959
    const int bb = wid & 15;                     // batch (batch-isolated wave)
    const int u  = wid >> 4;                     // 0..59
    const float* db = data + (size_t)bb * Nc * 3;
    const float* fb = feat + (size_t)bb * Nc * 3;

    float W[6];
#pragma unroll
    for (int c = 0; c < 6; ++c) W[c] = w0[lane * 6 + c];
    const float bias = b0[lane];
    float sum = 0.f, sq = 0.f;

    for (int s = u; s < Sc; s += 60) {
      const int q = bb * Sc + s;

      // prefetch chunk 0 while (possibly) waiting for the centroid index
      float px = db[lane * 3 + 0];
      float py = db[lane * 3 + 1];
      float pz = db[lane * 3 + 2];

      int ci;
      for (;;) {
        int t0 = -1;
        if (lane == 0) t0 = atomicAdd(&idx_pub[q], 0);  // coherent RMW read
        ci = __shfl(t0, 0);
        if (ci >= 0) break;
        __builtin_amdgcn_s_sleep(32);   // ~2k cycles between polls
      }

      const float qx = db[ci * 3 + 0];
      const float qy = db[ci * 3 + 1];
      const float qz = db[ci * 3 + 2];
      const float q2 = __fadd_rn(__fadd_rn(__fmul_rn(qx, qx), __fmul_rn(qy, qy)),
                                 __fmul_rn(qz, qz));

      // branchless fixed-trip scan: bit-identical nbr/have (write-guard
      // pos<Kc; popcll(0)=0), but no ballot->break serialization.
      int have = 0;
      for (int base = 0; base < Nc; base += 64) {
        const int inext = (base + 64 + lane) & (Nc - 1);
        float nx = db[inext * 3 + 0];
        float ny = db[inext * 3 + 1];
        float nz = db[inext * 3 + 2];

        float p2 = __fadd_rn(__fadd_rn(__fmul_rn(px, px), __fmul_rn(py, py)),
                             __fmul_rn(pz, pz));
        float dt = fmaf(qz, pz, fmaf(qy, py, __fmul_rn(qx, px)));
        float d = __fadd_rn(__fadd_rn(__fmul_rn(-2.0f, dt), q2), p2);
        bool ok = d <= 0.16f;
        unsigned long long mask = __ballot(ok);
        int pos = have + __popcll(mask & ((1ull << lane) - 1ull));
        if (ok && pos < Kc) nbr[w][pos] = base + lane;
        have += __popcll(mask);
        px = nx; py = ny; pz = nz;
      }
      if (have > Kc) have = Kc;

      // gather + x0 write (wave-local; compiler orders ds_write -> ds_read)
      if (lane < Kc) {
        int j = nbr[w][lane < have ? lane : 0];
        float sx = __fsub_rn(db[j * 3 + 0], qx);
        float sy = __fsub_rn(db[j * 3 + 1], qy);
        float sz = __fsub_rn(db[j * 3 + 2], qz);
        float fx = fb[j * 3 + 0], fy = fb[j * 3 + 1], fz = fb[j * 3 + 2];
        size_t pidx = (size_t)q * Kc + lane;
        x0[(size_t)0 * Pc + pidx] = sx;
        x0[(size_t)1 * Pc + pidx] = sy;
        x0[(size_t)2 * Pc + pidx] = sz;
        x0[(size_t)3 * Pc + pidx] = fx;
        x0[(size_t)4 * Pc + pidx] = fy;
        x0[(size_t)5 * Pc + pidx] = fz;
        x0s[w][0][lane] = sx; x0s[w][1][lane] = sy; x0s[w][2][lane] = sz;
        x0s[w][3][lane] = fx; x0s[w][4][lane] = fy; x0s[w][5][lane] = fz;
      }

      // y0 = conv0(x0)+b0 partial stats: lane = channel, broadcast LDS reads
#pragma unroll 4
      for (int k = 0; k < Kc; ++k) {
        float y = bias;
#pragma unroll
        for (int c = 0; c < 6; ++c) y = fmaf(x0s[w][c][k], W[c], y);
        sum += y;
        sq = fmaf(y, y, sq);
      }
    }
    part0[(size_t)wid * 128 + lane] = sum;
    part0[(size_t)wid * 128 + 64 + lane] = sq;
  }
}

// One block per channel; 256-thread fixed-order tree (deterministic, double).
__global__ __launch_bounds__(256)
void reduce_k(const float* __restrict__ part, int nblk, int nch,
              const float* __restrict__ g, const float* __restrict__ be,
              float* __restrict__ AB) {
  const int o = blockIdx.x;
  const int t = threadIdx.x;
  double sum = 0.0, sq = 0.0;
  for (int i = t; i < nblk; i += 256) {
    sum += (double)part[(size_t)i * (2 * nch) + o];
    sq  += (double)part[(size_t)i * (2 * nch) + nch + o];
  }
  __shared__ double ls[256], lq[256];
  ls[t] = sum; lq[t] = sq;
  __syncthreads();
  for (int s = 128; s > 0; s >>= 1) {
    if (t < s) { ls[t] += ls[t + s]; lq[t] += lq[t + s]; }
    __syncthreads();
  }
  if (t == 0) {
    double m = ls[0] / (double)Pc;
    double v = lq[0] / (double)Pc - m * m;
    double A = (double)g[o] / sqrt(v + 1e-5);
    AB[o] = (float)A;
    AB[nch + o] = (float)((double)be[o] - m * A);
  }
}

// reduce layer-2 stats fused with the final affine+relu epilogue.
__global__ __launch_bounds__(256)
void reduce2_final_k(const float* __restrict__ part, int nblk,
                     const float* __restrict__ g, const float* __restrict__ be,
                     const float* __restrict__ maxy2,
                     float* __restrict__ out) {
  const int o = blockIdx.x;          // 0..127
  const int t = threadIdx.x;
  double sum = 0.0, sq = 0.0;
  for (int i = t; i < nblk; i += 256) {
    sum += (double)part[(size_t)i * 256 + o];
    sq  += (double)part[(size_t)i * 256 + 128 + o];
  }
  __shared__ double ls[256], lq[256];
  ls[t] = sum; lq[t] = sq;
  __syncthreads();
  for (int s = 128; s > 0; s >>= 1) {
    if (t < s) { ls[t] += ls[t + s]; lq[t] += lq[t + s]; }
    __syncthreads();
  }
  __shared__ float sA, sB;
  if (t == 0) {
    double m = ls[0] / (double)Pc;
    double v = lq[0] / (double)Pc - m * m;
    double A = (double)g[o] / sqrt(v + 1e-5);
    sA = (float)A;
    sB = (float)((double)be[o] - m * A);
  }
  __syncthreads();
  const float A = sA, B = sB;
  for (int grp = t; grp < Bc * Sc; grp += 256) {
    float v = maxy2[(size_t)grp * 128 + o];
    out[(size_t)grp * 128 + o] = fmaxf(fmaf(v, A, B), 0.f);
  }
}

// ---------------------------------------------------------------------------
// pass_b (r14): exact r11 2-way form (best: 765.9us) + BLOCK-rotation of the
// o-loop start. r13: 4-way interleave regressed (791) -> 2-way is optimal.
// r12's wave-rotation was aimed wrong: SIMD s hosts wave s of ~4 DIFFERENT
// blocks, so same-SIMD waves shared weight lines anyway. Rotating by
// blockIdx desyncs co-resident waves' s_load drains (one wave's FMA block
// covers another's drain). Order change only: every (o,p) value, FP chain,
// and store address unchanged -> y1 bit-identical. Cost: 2 SALU.
// ---------------------------------------------------------------------------
__global__ __launch_bounds__(256, 1)
void pass_b(const float* __restrict__ x0, const float* __restrict__ w0,
            const float* __restrict__ b0, const float* __restrict__ AB0,
            const float* __restrict__ w1, const float* __restrict__ b1,
            float* __restrict__ y1) {
  const int p = blockIdx.x * 256 + threadIdx.x;
  const int obase = (blockIdx.x & 3) << 4;   // 0,16,32,48

  float xin[6];
#pragma unroll
  for (int c = 0; c < 6; ++c) xin[c] = x0[(size_t)c * Pc + p];

  v2f x1p[32];
#pragma unroll
  for (int j = 0; j < 32; ++j) {
    float y0v = b0[2 * j];
#pragma unroll
    for (int c = 0; c < 6; ++c) y0v = fmaf(xin[c], w0[(2 * j) * 6 + c], y0v);
    x1p[j].x = fmaxf(fmaf(y0v, AB0[2 * j], AB0[64 + 2 * j]), 0.f);
    float y1v = b0[2 * j + 1];
#pragma unroll
    for (int c = 0; c < 6; ++c) y1v = fmaf(xin[c], w0[(2 * j + 1) * 6 + c], y1v);
    x1p[j].y = fmaxf(fmaf(y1v, AB0[2 * j + 1], AB0[64 + 2 * j + 1]), 0.f);
  }

  const v2f* __restrict__ w1v = (const v2f*)w1;

  for (int oi = 0; oi < 64; oi += 2) {
    const int o = (oi + obase) & 63;         // even; block-rotated order
    v2f a01; a01.x = b1[o];     a01.y = 0.f;
    v2f a23; a23.x = 0.f;       a23.y = 0.f;
    v2f c01; c01.x = b1[o + 1]; c01.y = 0.f;
    v2f c23; c23.x = 0.f;       c23.y = 0.f;
#pragma unroll
    for (int c2 = 0; c2 < 32; c2 += 2) {
      a01 = PKFMA(x1p[c2 + 0], w1v[o * 32 + c2 + 0], a01);
      a23 = PKFMA(x1p[c2 + 1], w1v[o * 32 + c2 + 1], a23);
      c01 = PKFMA(x1p[c2 + 0], w1v[(o + 1) * 32 + c2 + 0], c01);
      c23 = PKFMA(x1p[c2 + 1], w1v[(o + 1) * 32 + c2 + 1], c23);
    }
    y1[(size_t)o * Pc + p]       = (a01.x + a01.y) + (a23.x + a23.y);
    y1[(size_t)(o + 1) * Pc + p] = (c01.x + c01.y) + (c23.x + c23.y);
  }
}

// stats1_k: per-channel sum/sumsq partials from the y1 planes (r9 form).
__global__ __launch_bounds__(256)
void stats1_k(const float* __restrict__ y1, float* __restrict__ pair1) {
  const int b = blockIdx.x;
  const int o = b >> 4, seg = b & 15;
  const int t = threadIdx.x;
  const float* plane = y1 + (size_t)o * Pc + (size_t)seg * 16384;
  float sum = 0.f, sq = 0.f;
  for (int i = t; i < 16384; i += 256) {
    float v = plane[i];
    sum += v;
    sq = fmaf(v, v, sq);
  }
  __shared__ float ls[256], lq[256];
  ls[t] = sum; lq[t] = sq;
  __syncthreads();
  for (int s = 128; s > 0; s >>= 1) {
    if (t < s) { ls[t] += ls[t + s]; lq[t] += lq[t + s]; }
    __syncthreads();
  }
  if (t == 0) {
    pair1[(size_t)b * 2 + 0] = ls[0];
    pair1[(size_t)b * 2 + 1] = lq[0];
  }
}

// Tiny deterministic double reduce over the 16 segment pairs per channel.
__global__ __launch_bounds__(64)
void reduceAB_pairs_k(const float* __restrict__ pair, int nseg,
                      const float* __restrict__ g, const float* __restrict__ be,
                      float* __restrict__ AB, int nch) {
  const int o = blockIdx.x;
  if (threadIdx.x == 0) {
    double sum = 0.0, sq = 0.0;
    for (int s = 0; s < nseg; ++s) {
      sum += (double)pair[(size_t)(o * nseg + s) * 2 + 0];
      sq  += (double)pair[(size_t)(o * nseg + s) * 2 + 1];
    }
    double m = sum / (double)Pc;
    double v = sq / (double)Pc - m * m;
    double A = (double)g[o] / sqrt(v + 1e-5);
    AB[o] = (float)A;
    AB[nch + o] = (float)((double)be[o] - m * A);
  }
}

// ---------------------------------------------------------------------------
// pass_c (r14): exact r11 2-way form + block-rotation (o start = (blk&3)*32).
// Per-o conv math, maxy2 shfl-tree, stats epilogues, FP order unchanged per
// o -> maxy2/part2 bit-identical to r11 (order of writes differs only).
// ---------------------------------------------------------------------------
__global__ __launch_bounds__(256, 1)
void pass_c(const float* __restrict__ y1, const float* __restrict__ AB1,
            const float* __restrict__ w2, const float* __restrict__ b2,
            float* __restrict__ maxy2, float* __restrict__ part2) {
  const int p = blockIdx.x * 256 + threadIdx.x;
  const int lane = threadIdx.x & 63, w = threadIdx.x >> 6;
  const int grp = p >> 5;
  const int obase = (blockIdx.x & 3) << 5;   // 0,32,64,96

  v2f x2p[32];
#pragma unroll
  for (int c = 0; c < 64; c += 2) {
    float v0 = y1[(size_t)c * Pc + p];
    float v1 = y1[(size_t)(c + 1) * Pc + p];
    x2p[c >> 1].x = fmaxf(fmaf(v0, AB1[c], AB1[64 + c]), 0.f);
    x2p[c >> 1].y = fmaxf(fmaf(v1, AB1[c + 1], AB1[64 + c + 1]), 0.f);
  }

  const v2f* __restrict__ w2v = (const v2f*)w2;

  __shared__ float ssum[4][128][9], ssq[4][128][9];  // padded: stride 9

  for (int oi = 0; oi < 128; oi += 2) {
    const int o = (oi + obase) & 127;        // even; block-rotated order
    v2f a01; a01.x = b2[o];     a01.y = 0.f;
    v2f a23; a23.x = 0.f;       a23.y = 0.f;
    v2f c01; c01.x = b2[o + 1]; c01.y = 0.f;
    v2f c23; c23.x = 0.f;       c23.y = 0.f;
#pragma unroll
    for (int c2 = 0; c2 < 32; c2 += 2) {
      a01 = PKFMA(x2p[c2 + 0], w2v[o * 32 + c2 + 0], a01);
      a23 = PKFMA(x2p[c2 + 1], w2v[o * 32 + c2 + 1], a23);
      c01 = PKFMA(x2p[c2 + 0], w2v[(o + 1) * 32 + c2 + 0], c01);
      c23 = PKFMA(x2p[c2 + 1], w2v[(o + 1) * 32 + c2 + 1], c23);
    }
    float acc0 = (a01.x + a01.y) + (a23.x + a23.y);
    float acc1 = (c01.x + c01.y) + (c23.x + c23.y);

    // epilogue for channel o (unchanged per-o logic)
    {
      float mx = acc0;
#pragma unroll
      for (int off = 16; off > 0; off >>= 1) mx = fmaxf(mx, __shfl_xor(mx, off));
      if ((lane & 31) == 0) maxy2[(size_t)grp * 128 + o] = mx;

      float sv = acc0 + __shfl_xor(acc0, 1);
      sv += __shfl_xor(sv, 2);
      sv += __shfl_xor(sv, 4);
      float q = acc0 * acc0;
      float qv = q + __shfl_xor(q, 1);
      qv += __shfl_xor(qv, 2);
      qv += __shfl_xor(qv, 4);
      if ((lane & 7) == 0) {
        ssum[w][o][lane >> 3] = sv;
        ssq[w][o][lane >> 3] = qv;
      }
    }
    // epilogue for channel o+1
    {
      float mx = acc1;
#pragma unroll
      for (int off = 16; off > 0; off >>= 1) mx = fmaxf(mx, __shfl_xor(mx, off));
      if ((lane & 31) == 0) maxy2[(size_t)grp * 128 + o + 1] = mx;

      float sv = acc1 + __shfl_xor(acc1, 1);
      sv += __shfl_xor(sv, 2);
      sv += __shfl_xor(sv, 4);
      float q = acc1 * acc1;
      float qv = q + __shfl_xor(q, 1);
      qv += __shfl_xor(qv, 2);
      qv += __shfl_xor(qv, 4);
      if ((lane & 7) == 0) {
        ssum[w][o + 1][lane >> 3] = sv;
        ssq[w][o + 1][lane >> 3] = qv;
      }
    }
  }
  __syncthreads();
  {
    const int o = threadIdx.x & 127;
    const bool isq = threadIdx.x >= 128;
    float s = 0.f;
#pragma unroll
    for (int ww = 0; ww < 4; ++ww)
      for (int k = 0; k < 8; ++k)
        s += isq ? ssq[ww][o][k] : ssum[ww][o][k];
    part2[blockIdx.x * 256 + threadIdx.x] = s;
  }
}

extern "C" void kernel_launch(void* const* d_in, const int* in_sizes, int n_in,
                              void* d_out, int out_size, void* d_ws, size_t ws_size,
                              hipStream_t stream) {
  const float* data = (const float*)d_in[0];
  const float* feat = (const float*)d_in[1];
  const float* w0 = (const float*)d_in[2];
  const float* b0 = (const float*)d_in[3];
  const float* g0 = (const float*)d_in[4];
  const float* be0 = (const float*)d_in[5];
  const float* w1 = (const float*)d_in[6];
  const float* b1 = (const float*)d_in[7];
  const float* g1 = (const float*)d_in[8];
  const float* be1 = (const float*)d_in[9];
  const float* w2 = (const float*)d_in[10];
  const float* b2 = (const float*)d_in[11];
  const float* g2 = (const float*)d_in[12];
  const float* be2 = (const float*)d_in[13];
  float* out = (float*)d_out;

  float* ws = (float*)d_ws;
  int* idx_pub = (int*)ws; ws += (size_t)Bc * Sc;      // 8192 ints
  float* x0 = ws;      ws += (size_t)6 * Pc;
  float* y1 = ws;      ws += (size_t)64 * Pc;          // [ch][point] planes
  float* maxy2 = ws;   ws += (size_t)Bc * Sc * 128;
  float* part0 = ws;   ws += (size_t)NBALL_WAVES * 128;
  float* pair1 = ws;   ws += 1024 * 2;
  float* part2 = ws;   ws += 1024 * 256;
  float* AB0 = ws;     ws += 128;
  float* AB1 = ws;     ws += 128;

  // re-poison the publication slots every graph replay
  hipMemsetAsync(idx_pub, 0xFF, (size_t)Bc * Sc * sizeof(int), stream);

  fps_ball_fused<<<Bc + NBALL_BLK, 256, 0, stream>>>(data, feat, w0, b0,
                                                     idx_pub, out, x0, part0);
  reduce_k<<<64, 256, 0, stream>>>(part0, NBALL_WAVES, 64, g0, be0, AB0);
  pass_b<<<Pc / 256, 256, 0, stream>>>(x0, w0, b0, AB0, w1, b1, y1);
  stats1_k<<<1024, 256, 0, stream>>>(y1, pair1);
  reduceAB_pairs_k<<<64, 64, 0, stream>>>(pair1, 16, g1, be1, AB1, 64);
  pass_c<<<Pc / 256, 256, 0, stream>>>(y1, AB1, w2, b2, maxy2, part2);
  reduce2_final_k<<<128, 256, 0, stream>>>(part2, 1024, g2, be2, maxy2,
                                           out + (size_t)Bc * Sc * 3);
}

// Round 15
// 736.473 us; speedup vs baseline: 1.1443x; 1.0012x over previous
//
#include <hip/hip_runtime.h>
#include <math.h>

constexpr int Bc = 16;
constexpr int Nc = 8192;
constexpr int Sc = 512;
constexpr int Kc = 32;
constexpr int Pc = Bc * Sc * Kc; // 262144

constexpr int NBALL_BLK = 240;             // ball blocks (+16 FPS = 256 total)
constexpr int NBALL_WAVES = NBALL_BLK * 4; // 960 (60 waves per batch, stride 60)

typedef float v2f __attribute__((ext_vector_type(2)));

#if defined(__has_builtin)
#if __has_builtin(__builtin_elementwise_fma)
#define PKFMA(a, b, c) __builtin_elementwise_fma(a, b, c)
#endif
#endif
#ifndef PKFMA
__device__ __forceinline__ v2f pkfma_(v2f a, v2f b, v2f c) {
  v2f r; r.x = fmaf(a.x, b.x, c.x); r.y = fmaf(a.y, b.y, c.y); return r;
}
#define PKFMA(a, b, c) pkfma_(a, b, c)
#endif

// DPP-assisted wave64 max stage (ctrl is a compile-time constant)
template <int CTRL>
__device__ __forceinline__ float dpp_max_stage(float x) {
  int p = __builtin_amdgcn_update_dpp(0, __float_as_int(x), CTRL, 0xf, 0xf, true);
  return fmaxf(x, __int_as_float(p));
}

// ---------------------------------------------------------------------------
// Fused FPS + ball query kernel — r14 form (475us measured; branchless scan
// confirmed -13us). Do not touch.
// ---------------------------------------------------------------------------
__global__ __launch_bounds__(256, 1)
void fps_ball_fused(const float* __restrict__ data,
                    const float* __restrict__ feat,
                    const float* __restrict__ w0,
                    const float* __restrict__ b0,
                    int* __restrict__ idx_pub,
                    float* __restrict__ cent_out,
                    float* __restrict__ x0,
                    float* __restrict__ part0) {
  __shared__ float lx[Nc], ly[Nc], lz[Nc];          // 96 KB point mirror (FPS)
  __shared__ unsigned long long red_k[2][4];
  __shared__ int idx_hist[Sc];
  __shared__ int nbr[4][Kc];                        // per-wave (ball)
  __shared__ float x0s[4][6][Kc];                   // per-wave (ball)

  const int t = threadIdx.x;
  const int lane = t & 63, w = t >> 6;

  if (blockIdx.x < Bc) {
    // ------------------------------ FPS ---------------------------------
    const int b = blockIdx.x;
    const float* db = data + (size_t)b * Nc * 3;

    float px[32], py[32], pz[32], dist[32];
#pragma unroll
    for (int j = 0; j < 32; ++j) {
      int p = t + 256 * j;
      px[j] = db[p * 3 + 0];
      py[j] = db[p * 3 + 1];
      pz[j] = db[p * 3 + 2];
      dist[j] = 1e10f;
      lx[p] = px[j]; ly[p] = py[j]; lz[p] = pz[j];
    }
    __syncthreads();

    int far = 0;
    for (int it = 0; it < Sc; ++it) {
      const int sfar = __builtin_amdgcn_readfirstlane(far);
      if (t == 0) {
        idx_hist[it] = sfar;
        atomicExch(&idx_pub[(b << 9) + it], sfar);  // publish, fire-and-forget
      }
      const float cx = lx[sfar];
      const float cy = ly[sfar];
      const float cz = lz[sfar];

      float best = -1.0f; int bj = 0;
#pragma unroll
      for (int j = 0; j < 32; ++j) {
        float dx = __fsub_rn(px[j], cx);
        float dy = __fsub_rn(py[j], cy);
        float dz = __fsub_rn(pz[j], cz);
        float d = __fadd_rn(__fadd_rn(__fmul_rn(dx, dx), __fmul_rn(dy, dy)),
                            __fmul_rn(dz, dz));
        float nd = fminf(dist[j], d);
        dist[j] = nd;
        if (nd > best) { best = nd; bj = j; }  // strict >: first index in lane
      }
      const int bidx = t + 256 * bj;

      float wmax = best;
      wmax = dpp_max_stage<0xB1>(wmax);   // quad_perm [1,0,3,2]
      wmax = dpp_max_stage<0x4E>(wmax);   // quad_perm [2,3,0,1]
      wmax = dpp_max_stage<0x141>(wmax);  // row_half_mirror
      wmax = dpp_max_stage<0x140>(wmax);  // row_mirror
      wmax = fmaxf(wmax, __shfl_xor(wmax, 16));
      wmax = fmaxf(wmax, __shfl_xor(wmax, 32));

      unsigned long long m = __ballot(best == wmax);
      int idx;
      if (__popcll(m) == 1) {
        idx = __shfl(bidx, (int)__ffsll((long long)m) - 1);
      } else {
        int cand = (best == wmax) ? bidx : 0x7fffffff;
#pragma unroll
        for (int off = 32; off; off >>= 1) cand = min(cand, __shfl_xor(cand, off));
        idx = cand;
      }

      unsigned long long key =
          ((unsigned long long)__float_as_uint(wmax) << 32) |
          (unsigned long long)(0xFFFFFFFFu - (unsigned)idx);
      const int par = it & 1;
      if (lane == 0) red_k[par][w] = key;
      __syncthreads();

      unsigned long long k0 = red_k[par][0];
      unsigned long long k1 = red_k[par][1];
      unsigned long long k2 = red_k[par][2];
      unsigned long long k3 = red_k[par][3];
      unsigned long long ka = (k0 > k1) ? k0 : k1;
      unsigned long long kb = (k2 > k3) ? k2 : k3;
      unsigned long long kk = (ka > kb) ? ka : kb;
      far = (int)(0xFFFFFFFFu - (unsigned)(kk & 0xFFFFFFFFull));
    }

    __syncthreads();
    for (int s = t; s < Sc; s += 256) {
      int id = idx_hist[s];
      size_t o = ((size_t)b * Sc + s) * 3;
      cent_out[o + 0] = lx[id];
      cent_out[o + 1] = ly[id];
      cent_out[o + 2] = lz[id];
    }
  } else {
    // --------------------------- ball query ------------------------------
    const int wid = (blockIdx.x - Bc) * 4 + w;   // 0..959
    const int bb = wid & 15;                     // batch (batch-isolated wave)
    const int u  = wid >> 4;                     // 0..59
    const float* db = data + (size_t)bb * Nc * 3;
    const float* fb = feat + (size_t)bb * Nc * 3;

    float W[6];
#pragma unroll
    for (int c = 0; c < 6; ++c) W[c] = w0[lane * 6 + c];
    const float bias = b0[lane];
    float sum = 0.f, sq = 0.f;

    for (int s = u; s < Sc; s += 60) {
      const int q = bb * Sc + s;

      // prefetch chunk 0 while (possibly) waiting for the centroid index
      float px = db[lane * 3 + 0];
      float py = db[lane * 3 + 1];
      float pz = db[lane * 3 + 2];

      int ci;
      for (;;) {
        int t0 = -1;
        if (lane == 0) t0 = atomicAdd(&idx_pub[q], 0);  // coherent RMW read
        ci = __shfl(t0, 0);
        if (ci >= 0) break;
        __builtin_amdgcn_s_sleep(32);   // ~2k cycles between polls
      }

      const float qx = db[ci * 3 + 0];
      const float qy = db[ci * 3 + 1];
      const float qz = db[ci * 3 + 2];
      const float q2 = __fadd_rn(__fadd_rn(__fmul_rn(qx, qx), __fmul_rn(qy, qy)),
                                 __fmul_rn(qz, qz));

      // branchless fixed-trip scan: bit-identical nbr/have (write-guard
      // pos<Kc; popcll(0)=0), but no ballot->break serialization.
      int have = 0;
      for (int base = 0; base < Nc; base += 64) {
        const int inext = (base + 64 + lane) & (Nc - 1);
        float nx = db[inext * 3 + 0];
        float ny = db[inext * 3 + 1];
        float nz = db[inext * 3 + 2];

        float p2 = __fadd_rn(__fadd_rn(__fmul_rn(px, px), __fmul_rn(py, py)),
                             __fmul_rn(pz, pz));
        float dt = fmaf(qz, pz, fmaf(qy, py, __fmul_rn(qx, px)));
        float d = __fadd_rn(__fadd_rn(__fmul_rn(-2.0f, dt), q2), p2);
        bool ok = d <= 0.16f;
        unsigned long long mask = __ballot(ok);
        int pos = have + __popcll(mask & ((1ull << lane) - 1ull));
        if (ok && pos < Kc) nbr[w][pos] = base + lane;
        have += __popcll(mask);
        px = nx; py = ny; pz = nz;
      }
      if (have > Kc) have = Kc;

      // gather + x0 write (wave-local; compiler orders ds_write -> ds_read)
      if (lane < Kc) {
        int j = nbr[w][lane < have ? lane : 0];
        float sx = __fsub_rn(db[j * 3 + 0], qx);
        float sy = __fsub_rn(db[j * 3 + 1], qy);
        float sz = __fsub_rn(db[j * 3 + 2], qz);
        float fx = fb[j * 3 + 0], fy = fb[j * 3 + 1], fz = fb[j * 3 + 2];
        size_t pidx = (size_t)q * Kc + lane;
        x0[(size_t)0 * Pc + pidx] = sx;
        x0[(size_t)1 * Pc + pidx] = sy;
        x0[(size_t)2 * Pc + pidx] = sz;
        x0[(size_t)3 * Pc + pidx] = fx;
        x0[(size_t)4 * Pc + pidx] = fy;
        x0[(size_t)5 * Pc + pidx] = fz;
        x0s[w][0][lane] = sx; x0s[w][1][lane] = sy; x0s[w][2][lane] = sz;
        x0s[w][3][lane] = fx; x0s[w][4][lane] = fy; x0s[w][5][lane] = fz;
      }

      // y0 = conv0(x0)+b0 partial stats: lane = channel, broadcast LDS reads
#pragma unroll 4
      for (int k = 0; k < Kc; ++k) {
        float y = bias;
#pragma unroll
        for (int c = 0; c < 6; ++c) y = fmaf(x0s[w][c][k], W[c], y);
        sum += y;
        sq = fmaf(y, y, sq);
      }
    }
    part0[(size_t)wid * 128 + lane] = sum;
    part0[(size_t)wid * 128 + 64 + lane] = sq;
  }
}

// One block per channel; 256-thread fixed-order tree (deterministic, double).
__global__ __launch_bounds__(256)
void reduce_k(const float* __restrict__ part, int nblk, int nch,
              const float* __restrict__ g, const float* __restrict__ be,
              float* __restrict__ AB) {
  const int o = blockIdx.x;
  const int t = threadIdx.x;
  double sum = 0.0, sq = 0.0;
  for (int i = t; i < nblk; i += 256) {
    sum += (double)part[(size_t)i * (2 * nch) + o];
    sq  += (double)part[(size_t)i * (2 * nch) + nch + o];
  }
  __shared__ double ls[256], lq[256];
  ls[t] = sum; lq[t] = sq;
  __syncthreads();
  for (int s = 128; s > 0; s >>= 1) {
    if (t < s) { ls[t] += ls[t + s]; lq[t] += lq[t + s]; }
    __syncthreads();
  }
  if (t == 0) {
    double m = ls[0] / (double)Pc;
    double v = lq[0] / (double)Pc - m * m;
    double A = (double)g[o] / sqrt(v + 1e-5);
    AB[o] = (float)A;
    AB[nch + o] = (float)((double)be[o] - m * A);
  }
}

// reduce layer-2 stats fused with the final affine+relu epilogue.
__global__ __launch_bounds__(256)
void reduce2_final_k(const float* __restrict__ part, int nblk,
                     const float* __restrict__ g, const float* __restrict__ be,
                     const float* __restrict__ maxy2,
                     float* __restrict__ out) {
  const int o = blockIdx.x;          // 0..127
  const int t = threadIdx.x;
  double sum = 0.0, sq = 0.0;
  for (int i = t; i < nblk; i += 256) {
    sum += (double)part[(size_t)i * 256 + o];
    sq  += (double)part[(size_t)i * 256 + 128 + o];
  }
  __shared__ double ls[256], lq[256];
  ls[t] = sum; lq[t] = sq;
  __syncthreads();
  for (int s = 128; s > 0; s >>= 1) {
    if (t < s) { ls[t] += ls[t + s]; lq[t] += lq[t + s]; }
    __syncthreads();
  }
  __shared__ float sA, sB;
  if (t == 0) {
    double m = ls[0] / (double)Pc;
    double v = lq[0] / (double)Pc - m * m;
    double A = (double)g[o] / sqrt(v + 1e-5);
    sA = (float)A;
    sB = (float)((double)be[o] - m * A);
  }
  __syncthreads();
  const float A = sA, B = sB;
  for (int grp = t; grp < Bc * Sc; grp += 256) {
    float v = maxy2[(size_t)grp * 128 + o];
    out[(size_t)grp * 128 + o] = fmaxf(fmaf(v, A, B), 0.f);
  }
}

// ---------------------------------------------------------------------------
// pass_b (r15): r14-exact (2-way interleave + block rotation, 737us total)
// + VECTOR-PATH weight loads. Theory: wave-uniform const weight reads get
// scalarized to s_load batches into SGPRs; 2 rows/iter = 512B = 128 SGPR >
// budget -> several small batches, several lgkmcnt drains per o-pair at
// scalar-L2 latency (this is the residual downstream stall; also explains
// why 4-way interleave regressed: SGPR pressure). Fix: route a runtime-zero
// through __shfl (ds_bpermute result is divergence-opaque) and offset the
// weight pointer by it -> addresses formally per-lane -> global_load_dwordx4
// (vmcnt-pipelined, 64-deep queue, loads of iter i+1 overlap FMAs of iter i;
// all lanes hit the same line -> broadcast). Values identical -> bit-exact.
// ---------------------------------------------------------------------------
__global__ __launch_bounds__(256, 1)
void pass_b(const float* __restrict__ x0, const float* __restrict__ w0,
            const float* __restrict__ b0, const float* __restrict__ AB0,
            const float* __restrict__ w1, const float* __restrict__ b1,
            float* __restrict__ y1, int zk) {
  const int p = blockIdx.x * 256 + threadIdx.x;
  const int obase = (blockIdx.x & 3) << 4;   // 0,16,32,48

  float xin[6];
#pragma unroll
  for (int c = 0; c < 6; ++c) xin[c] = x0[(size_t)c * Pc + p];

  v2f x1p[32];
#pragma unroll
  for (int j = 0; j < 32; ++j) {
    float y0v = b0[2 * j];
#pragma unroll
    for (int c = 0; c < 6; ++c) y0v = fmaf(xin[c], w0[(2 * j) * 6 + c], y0v);
    x1p[j].x = fmaxf(fmaf(y0v, AB0[2 * j], AB0[64 + 2 * j]), 0.f);
    float y1v = b0[2 * j + 1];
#pragma unroll
    for (int c = 0; c < 6; ++c) y1v = fmaf(xin[c], w0[(2 * j + 1) * 6 + c], y1v);
    x1p[j].y = fmaxf(fmaf(y1v, AB0[2 * j + 1], AB0[64 + 2 * j + 1]), 0.f);
  }

  // vz == 0 at runtime; divergence-opaque -> forces vector-path weight loads
  const int vz = __shfl(zk, 0);
  const v2f* __restrict__ w1v = (const v2f*)w1 + vz;

  for (int oi = 0; oi < 64; oi += 2) {
    const int o = (oi + obase) & 63;         // even; block-rotated order
    v2f a01; a01.x = b1[o];     a01.y = 0.f;
    v2f a23; a23.x = 0.f;       a23.y = 0.f;
    v2f c01; c01.x = b1[o + 1]; c01.y = 0.f;
    v2f c23; c23.x = 0.f;       c23.y = 0.f;
#pragma unroll
    for (int c2 = 0; c2 < 32; c2 += 2) {
      a01 = PKFMA(x1p[c2 + 0], w1v[o * 32 + c2 + 0], a01);
      a23 = PKFMA(x1p[c2 + 1], w1v[o * 32 + c2 + 1], a23);
      c01 = PKFMA(x1p[c2 + 0], w1v[(o + 1) * 32 + c2 + 0], c01);
      c23 = PKFMA(x1p[c2 + 1], w1v[(o + 1) * 32 + c2 + 1], c23);
    }
    y1[(size_t)o * Pc + p]       = (a01.x + a01.y) + (a23.x + a23.y);
    y1[(size_t)(o + 1) * Pc + p] = (c01.x + c01.y) + (c23.x + c23.y);
  }
}

// stats1_k: per-channel sum/sumsq partials from the y1 planes (r9 form).
__global__ __launch_bounds__(256)
void stats1_k(const float* __restrict__ y1, float* __restrict__ pair1) {
  const int b = blockIdx.x;
  const int o = b >> 4, seg = b & 15;
  const int t = threadIdx.x;
  const float* plane = y1 + (size_t)o * Pc + (size_t)seg * 16384;
  float sum = 0.f, sq = 0.f;
  for (int i = t; i < 16384; i += 256) {
    float v = plane[i];
    sum += v;
    sq = fmaf(v, v, sq);
  }
  __shared__ float ls[256], lq[256];
  ls[t] = sum; lq[t] = sq;
  __syncthreads();
  for (int s = 128; s > 0; s >>= 1) {
    if (t < s) { ls[t] += ls[t + s]; lq[t] += lq[t + s]; }
    __syncthreads();
  }
  if (t == 0) {
    pair1[(size_t)b * 2 + 0] = ls[0];
    pair1[(size_t)b * 2 + 1] = lq[0];
  }
}

// Tiny deterministic double reduce over the 16 segment pairs per channel.
__global__ __launch_bounds__(64)
void reduceAB_pairs_k(const float* __restrict__ pair, int nseg,
                      const float* __restrict__ g, const float* __restrict__ be,
                      float* __restrict__ AB, int nch) {
  const int o = blockIdx.x;
  if (threadIdx.x == 0) {
    double sum = 0.0, sq = 0.0;
    for (int s = 0; s < nseg; ++s) {
      sum += (double)pair[(size_t)(o * nseg + s) * 2 + 0];
      sq  += (double)pair[(size_t)(o * nseg + s) * 2 + 1];
    }
    double m = sum / (double)Pc;
    double v = sq / (double)Pc - m * m;
    double A = (double)g[o] / sqrt(v + 1e-5);
    AB[o] = (float)A;
    AB[nch + o] = (float)((double)be[o] - m * A);
  }
}

// ---------------------------------------------------------------------------
// pass_c (r15): r14-exact + vector-path weight loads (same vz trick).
// Per-o conv math, maxy2 shfl-tree, stats epilogues, FP order unchanged
// -> maxy2/part2 bit-identical.
// ---------------------------------------------------------------------------
__global__ __launch_bounds__(256, 1)
void pass_c(const float* __restrict__ y1, const float* __restrict__ AB1,
            const float* __restrict__ w2, const float* __restrict__ b2,
            float* __restrict__ maxy2, float* __restrict__ part2, int zk) {
  const int p = blockIdx.x * 256 + threadIdx.x;
  const int lane = threadIdx.x & 63, w = threadIdx.x >> 6;
  const int grp = p >> 5;
  const int obase = (blockIdx.x & 3) << 5;   // 0,32,64,96

  v2f x2p[32];
#pragma unroll
  for (int c = 0; c < 64; c += 2) {
    float v0 = y1[(size_t)c * Pc + p];
    float v1 = y1[(size_t)(c + 1) * Pc + p];
    x2p[c >> 1].x = fmaxf(fmaf(v0, AB1[c], AB1[64 + c]), 0.f);
    x2p[c >> 1].y = fmaxf(fmaf(v1, AB1[c + 1], AB1[64 + c + 1]), 0.f);
  }

  // vz == 0 at runtime; divergence-opaque -> forces vector-path weight loads
  const int vz = __shfl(zk, 0);
  const v2f* __restrict__ w2v = (const v2f*)w2 + vz;

  __shared__ float ssum[4][128][9], ssq[4][128][9];  // padded: stride 9

  for (int oi = 0; oi < 128; oi += 2) {
    const int o = (oi + obase) & 127;        // even; block-rotated order
    v2f a01; a01.x = b2[o];     a01.y = 0.f;
    v2f a23; a23.x = 0.f;       a23.y = 0.f;
    v2f c01; c01.x = b2[o + 1]; c01.y = 0.f;
    v2f c23; c23.x = 0.f;       c23.y = 0.f;
#pragma unroll
    for (int c2 = 0; c2 < 32; c2 += 2) {
      a01 = PKFMA(x2p[c2 + 0], w2v[o * 32 + c2 + 0], a01);
      a23 = PKFMA(x2p[c2 + 1], w2v[o * 32 + c2 + 1], a23);
      c01 = PKFMA(x2p[c2 + 0], w2v[(o + 1) * 32 + c2 + 0], c01);
      c23 = PKFMA(x2p[c2 + 1], w2v[(o + 1) * 32 + c2 + 1], c23);
    }
    float acc0 = (a01.x + a01.y) + (a23.x + a23.y);
    float acc1 = (c01.x + c01.y) + (c23.x + c23.y);

    // epilogue for channel o (unchanged per-o logic)
    {
      float mx = acc0;
#pragma unroll
      for (int off = 16; off > 0; off >>= 1) mx = fmaxf(mx, __shfl_xor(mx, off));
      if ((lane & 31) == 0) maxy2[(size_t)grp * 128 + o] = mx;

      float sv = acc0 + __shfl_xor(acc0, 1);
      sv += __shfl_xor(sv, 2);
      sv += __shfl_xor(sv, 4);
      float q = acc0 * acc0;
      float qv = q + __shfl_xor(q, 1);
      qv += __shfl_xor(qv, 2);
      qv += __shfl_xor(qv, 4);
      if ((lane & 7) == 0) {
        ssum[w][o][lane >> 3] = sv;
        ssq[w][o][lane >> 3] = qv;
      }
    }
    // epilogue for channel o+1
    {
      float mx = acc1;
#pragma unroll
      for (int off = 16; off > 0; off >>= 1) mx = fmaxf(mx, __shfl_xor(mx, off));
      if ((lane & 31) == 0) maxy2[(size_t)grp * 128 + o + 1] = mx;

      float sv = acc1 + __shfl_xor(acc1, 1);
      sv += __shfl_xor(sv, 2);
      sv += __shfl_xor(sv, 4);
      float q = acc1 * acc1;
      float qv = q + __shfl_xor(q, 1);
      qv += __shfl_xor(qv, 2);
      qv += __shfl_xor(qv, 4);
      if ((lane & 7) == 0) {
        ssum[w][o + 1][lane >> 3] = sv;
        ssq[w][o + 1][lane >> 3] = qv;
      }
    }
  }
  __syncthreads();
  {
    const int o = threadIdx.x & 127;
    const bool isq = threadIdx.x >= 128;
    float s = 0.f;
#pragma unroll
    for (int ww = 0; ww < 4; ++ww)
      for (int k = 0; k < 8; ++k)
        s += isq ? ssq[ww][o][k] : ssum[ww][o][k];
    part2[blockIdx.x * 256 + threadIdx.x] = s;
  }
}

extern "C" void kernel_launch(void* const* d_in, const int* in_sizes, int n_in,
                              void* d_out, int out_size, void* d_ws, size_t ws_size,
                              hipStream_t stream) {
  const float* data = (const float*)d_in[0];
  const float* feat = (const float*)d_in[1];
  const float* w0 = (const float*)d_in[2];
  const float* b0 = (const float*)d_in[3];
  const float* g0 = (const float*)d_in[4];
  const float* be0 = (const float*)d_in[5];
  const float* w1 = (const float*)d_in[6];
  const float* b1 = (const float*)d_in[7];
  const float* g1 = (const float*)d_in[8];
  const float* be1 = (const float*)d_in[9];
  const float* w2 = (const float*)d_in[10];
  const float* b2 = (const float*)d_in[11];
  const float* g2 = (const float*)d_in[12];
  const float* be2 = (const float*)d_in[13];
  float* out = (float*)d_out;

  float* ws = (float*)d_ws;
  int* idx_pub = (int*)ws; ws += (size_t)Bc * Sc;      // 8192 ints
  float* x0 = ws;      ws += (size_t)6 * Pc;
  float* y1 = ws;      ws += (size_t)64 * Pc;          // [ch][point] planes
  float* maxy2 = ws;   ws += (size_t)Bc * Sc * 128;
  float* part0 = ws;   ws += (size_t)NBALL_WAVES * 128;
  float* pair1 = ws;   ws += 1024 * 2;
  float* part2 = ws;   ws += 1024 * 256;
  float* AB0 = ws;     ws += 128;
  float* AB1 = ws;     ws += 128;

  // re-poison the publication slots every graph replay
  hipMemsetAsync(idx_pub, 0xFF, (size_t)Bc * Sc * sizeof(int), stream);

  fps_ball_fused<<<Bc + NBALL_BLK, 256, 0, stream>>>(data, feat, w0, b0,
                                                     idx_pub, out, x0, part0);
  reduce_k<<<64, 256, 0, stream>>>(part0, NBALL_WAVES, 64, g0, be0, AB0);
  pass_b<<<Pc / 256, 256, 0, stream>>>(x0, w0, b0, AB0, w1, b1, y1, 0);
  stats1_k<<<1024, 256, 0, stream>>>(y1, pair1);
  reduceAB_pairs_k<<<64, 64, 0, stream>>>(pair1, 16, g1, be1, AB1, 64);
  pass_c<<<Pc / 256, 256, 0, stream>>>(y1, AB1, w2, b2, maxy2, part2, 0);
  reduce2_final_k<<<128, 256, 0, stream>>>(part2, 1024, g2, be2, maxy2,
                                           out + (size_t)Bc * Sc * 3);
}